// Round 5
// baseline (1278.566 us; speedup 1.0000x reference)
//
#include <hip/hip_runtime.h>
#include <hip/hip_bf16.h>
#include <math.h>

typedef __hip_bfloat16 bf16;
typedef __attribute__((ext_vector_type(8))) short bf16x8;   // 8 bf16 = 4 VGPR
typedef __attribute__((ext_vector_type(4))) float f32x4;    // MFMA acc

#define BATCH   16
#define SEQLEN  2048
#define INDIM   64
#define HIDD    256
#define STATE_D 256
#define MLPD    1024
#define OUTD    128
#define NLAYERS 4
#define M_TOK   (BATCH*SEQLEN)     // 32768 tokens
#define CHUNK   64
#define NCHUNK  (SEQLEN/CHUNK)     // 32 chunks per batch

// ---- fp32 masters (residual chain precision) -------------------------------
__device__ float g_h [(size_t)M_TOK*256];
__device__ float g_y [(size_t)M_TOK*256];
__device__ float g_bu[(size_t)M_TOK*512];
__device__ float g_carry[512*512];
// ---- bf16 shadows / packed weights (MFMA operands) -------------------------
__device__ bf16  g_hb [(size_t)M_TOK*256];
__device__ bf16  g_yb [(size_t)M_TOK*256];
__device__ bf16  g_bub[(size_t)M_TOK*512];
__device__ bf16  g_zb [(size_t)M_TOK*1024];
// per-layer packed weights (hoisted out of the layer loop)
__device__ bf16  g_Bnb[NLAYERS*512*256];    // B_norm: rows 0-255 re, 256-511 im
__device__ bf16  g_Cwb[NLAYERS*256*512];    // [Cre | -Cim]
__device__ bf16  g_Whb[NLAYERS*1024*256];
__device__ bf16  g_Wob[NLAYERS*256*1024];

#define SF_H  0
#define SF_Y  1
#define SF_BU 2
#define SB_HB  0
#define SB_YB  1
#define SB_BUB 2
#define SB_ZB  3
#define SB_BNB 4
#define SB_CWB 5
#define SB_WHB 6
#define SB_WOB 7

__device__ __forceinline__ float* buff(int sel){
  switch(sel){ case SF_H: return g_h; case SF_Y: return g_y; default: return g_bu; }
}
__device__ __forceinline__ bf16* bufb(int sel){
  switch(sel){
    case SB_HB:  return g_hb;  case SB_YB:  return g_yb;
    case SB_BUB: return g_bub; case SB_ZB:  return g_zb;
    case SB_BNB: return g_Bnb; case SB_CWB: return g_Cwb;
    case SB_WHB: return g_Whb; default:     return g_Wob; }
}

// async global->LDS, 16B per lane. LDS dest is wave-uniform base + lane*16.
__device__ __forceinline__ void gld_lds16(const void* g, void* l){
  __builtin_amdgcn_global_load_lds(
      (const __attribute__((address_space(1))) unsigned int*)g,
      (__attribute__((address_space(3))) unsigned int*)l, 16, 0, 0);
}

// Branch-free exact-GELU via Abramowitz-Stegun 7.1.26 erf (|err|<=1.5e-7,
// far below bf16 rounding). ~16 VALU, no divergence (verified R4: the
// 54%-VALUBusy erff dispatches left the top-5).
__device__ __forceinline__ float fast_gelu(float v){
  const float x  = v * 0.70710678118654752f;
  const float ax = fabsf(x);
  const float t  = __builtin_amdgcn_rcpf(fmaf(0.3275911f, ax, 1.0f));
  float p = fmaf(t, 1.061405429f, -1.453152027f);
  p = fmaf(t, p, 1.421413741f);
  p = fmaf(t, p, -0.284496736f);
  p = fmaf(t, p, 0.254829592f);
  p = p * t;
  const float e = __expf(-ax * ax);
  const float erf_ax = fmaf(-p, e, 1.0f);
  const float erf_x  = copysignf(erf_ax, x);
  return 0.5f * v * (1.0f + erf_x);
}

// ---------------------------------------------------------------------------
// MFMA GEMM: C[M,N] = act(A @ W^T + bias) (+res / +dscale*res)
// A: bf16 [M,K] lda;  W: bf16 [N,K] ldw (+wOff).
// 128x256 block tile (2 col-halves), 4 waves, BK=32, 3-deep LDS ring with
// counted vmcnt (R3-proven shape; R4's reg ping-pong reverted — it regressed).
// Wide tile rationale (R4 counters): Bu's A-panel was HBM-fetched ~3.2x
// because its 4 col-tiles landed on 4 different XCD L2s. 2 col-halves per
// block halve the sharer count and make the remaining sharers co-resident
// in the same XCD chunk; y/h (N=256) read the A panel exactly once.
// Per iter: vmcnt(tile t) -> barrier -> 12x ds_read_b128 -> lgkm(0) ->
// barrier -> STAGE(t+3, 6 loads) -> 32x MFMA.
// T2 swizzle (linear LDS dest + swizzled GLOBAL source) keeps ds_read
// conflict-free (verified 2.1M -> 0). XCD-chunked bijective blockIdx swizzle.
// FLAGS: 1=bias  2=add res  4=add dscale[n]*res.  ACT: 1=exact GELU (fast erf).
// ---------------------------------------------------------------------------
template<int ACT, int FLAGS>
__global__ __launch_bounds__(256, 2) void mfma_gemm(
    int aSel, int lda, int wSel, int wOff, int ldw,
    int oFSel, int oBSel, int ldc,
    const float* __restrict__ bias,
    int rSel, int ldres,
    const float* __restrict__ dscale,
    int K)
{
  const bf16* A = bufb(aSel);
  const bf16* W = bufb(wSel) + wOff;
  float* OF = (oFSel >= 0) ? buff(oFSel) : nullptr;
  bf16*  OB = (oBSel >= 0) ? bufb(oBSel) : nullptr;
  const float* res = (rSel >= 0) ? buff(rSel) : nullptr;

  __shared__ __align__(16) unsigned short As[3*128*32];   // 3 x 8 KB
  __shared__ __align__(16) unsigned short Ws[3*256*32];   // 3 x 16 KB

  // ---- XCD-chunked bijective blockIdx swizzle (m204 formula) ----
  const int gx = gridDim.x;
  const int nwg = gx * gridDim.y;
  const int orig = blockIdx.y * gx + blockIdx.x;
  const int q = nwg >> 3, r = nwg & 7;
  const int xcd = orig & 7, idx = orig >> 3;
  const int wg = (xcd < r ? xcd*(q+1) : r*(q+1) + (xcd-r)*q) + idx;
  const int bx = wg % gx, by = wg / gx;

  const int tid  = threadIdx.x;
  const int row0 = by * 128, col0 = bx * 256;
  const int lane = tid & 63;
  const int m16  = lane & 15, quad = lane >> 4;
  const int wv   = tid >> 6;
  const int wm   = (wv & 1) * 64, wn = (wv >> 1) * 64;

  // staging: wave w, lane l -> LDS row w*16 + (l>>2), slot (l&3).
  // Source k-group is XOR-swizzled by row ((r>>1)&3; consistent under r+=64).
  const int rlo = wv*16 + (lane >> 2);
  const int sg  = ((lane & 3) ^ ((rlo >> 1) & 3)) * 8;    // shorts
  const bf16* ga = &A[(size_t)(row0 + rlo)*lda + sg];
  const bf16* gw = &W[(size_t)(col0 + rlo)*ldw + sg];
  const size_t a64 = (size_t)64 * lda;
  const size_t w64 = (size_t)64 * ldw;

  auto STAGE = [&](int bb, int k0){
    unsigned short* Ab = As + bb*4096;
    unsigned short* Wb = Ws + bb*8192;
    gld_lds16(ga + k0,         Ab + wv*512);
    gld_lds16(ga + k0 +   a64, Ab + 2048 + wv*512);
    gld_lds16(gw + k0,         Wb + wv*512);
    gld_lds16(gw + k0 +   w64, Wb + 2048 + wv*512);
    gld_lds16(gw + k0 + 2*w64, Wb + 4096 + wv*512);
    gld_lds16(gw + k0 + 3*w64, Wb + 6144 + wv*512);
  };

  f32x4 acc0[4][4] = {};    // col-half 0
  f32x4 acc1[4][4] = {};    // col-half 1
  const int nt = K >> 5;    // 8/16/32 for our shapes

  STAGE(0, 0); STAGE(1, 32); STAGE(2, 64);   // 18 vm loads/wave in flight

  int b = 0;
  for (int t = 0; t < nt; ++t){
    // tile t resident when <= 6*(younger tiles staged) outstanding
    if (t + 2 < nt)      asm volatile("s_waitcnt vmcnt(12)" ::: "memory");
    else if (t + 1 < nt) asm volatile("s_waitcnt vmcnt(6)"  ::: "memory");
    else                 asm volatile("s_waitcnt vmcnt(0)"  ::: "memory");
    __builtin_amdgcn_s_barrier();            // all waves' portions resident

    const unsigned short* Ab = As + b*4096;
    const unsigned short* Wb = Ws + b*8192;
    bf16x8 af[4], wf0[4], wf1[4];
    #pragma unroll
    for (int i = 0; i < 4; i++){
      const int rA  = wm + 16*i + m16;
      const int rW0 = wn + 16*i + m16;
      const int rW1 = 128 + rW0;
      af[i]  = *reinterpret_cast<const bf16x8*>(&Ab[rA *32 + ((quad ^ ((rA >>1)&3))<<3)]);
      wf0[i] = *reinterpret_cast<const bf16x8*>(&Wb[rW0*32 + ((quad ^ ((rW0>>1)&3))<<3)]);
      wf1[i] = *reinterpret_cast<const bf16x8*>(&Wb[rW1*32 + ((quad ^ ((rW1>>1)&3))<<3)]);
    }
    asm volatile("s_waitcnt lgkmcnt(0)" ::: "memory");   // this wave's reads done
    __builtin_amdgcn_sched_barrier(0);                   // rule #18
    __builtin_amdgcn_s_barrier();                        // all waves done with buf b

    if (t + 3 < nt) STAGE(b, (t + 3) << 5);              // refill freed buffer

    __builtin_amdgcn_s_setprio(1);
    #pragma unroll
    for (int i = 0; i < 4; i++)
      #pragma unroll
      for (int j = 0; j < 4; j++)
        acc0[i][j] = __builtin_amdgcn_mfma_f32_16x16x32_bf16(af[i], wf0[j], acc0[i][j], 0, 0, 0);
    #pragma unroll
    for (int i = 0; i < 4; i++)
      #pragma unroll
      for (int j = 0; j < 4; j++)
        acc1[i][j] = __builtin_amdgcn_mfma_f32_16x16x32_bf16(af[i], wf1[j], acc1[i][j], 0, 0, 0);
    __builtin_amdgcn_s_setprio(0);

    b = (b == 2) ? 0 : b + 1;
  }

  // epilogue: C/D layout col=lane&15, row=quad*4+reg  (m89-verified)
  #pragma unroll
  for (int n = 0; n < 2; n++){
    #pragma unroll
    for (int i = 0; i < 4; i++){
      #pragma unroll
      for (int j = 0; j < 4; j++){
        const int col = col0 + n*128 + wn + 16*j + m16;
        #pragma unroll
        for (int r2 = 0; r2 < 4; r2++){
          const int row = row0 + wm + 16*i + quad*4 + r2;
          float v = (n == 0) ? acc0[i][j][r2] : acc1[i][j][r2];
          if (FLAGS & 1) v += bias[col];
          if (ACT == 1)  v = fast_gelu(v);
          if (FLAGS & 2) v += res[(size_t)row*ldres + col];
          if (FLAGS & 4) v += dscale[col] * res[(size_t)row*ldres + col];
          const size_t o = (size_t)row*ldc + col;
          if (OF) OF[o] = v;
          if (OB) OB[o] = __float2bfloat16(v);
        }
      }
    }
  }
}

// ---------------------------------------------------------------------------
// fp32 tiled GEMMs for the small ends (embed, out) — proven R12 structure.
// ---------------------------------------------------------------------------
__global__ __launch_bounds__(256) void emb_gemm(
    const float* __restrict__ x, const float* __restrict__ W,
    const float* __restrict__ b)
{
  __shared__ __align__(16) float Asx[16][68];
  __shared__ __align__(16) float Wsx[16][68];
  const int tid = threadIdx.x;
  const int tx = tid & 15, ty = tid >> 4;
  const int row0 = blockIdx.y * 64, col0 = blockIdx.x * 64;
  const int lc = tid & 15, lr = tid >> 4;
  float acc[4][4] = {};
  for (int k0 = 0; k0 < INDIM; k0 += 16){
    #pragma unroll
    for (int i = 0; i < 4; i++){
      Asx[lc][lr + 16*i] = x[(size_t)(row0 + lr + 16*i)*INDIM + k0 + lc];
      Wsx[lc][lr + 16*i] = W[(size_t)(col0 + lr + 16*i)*INDIM + k0 + lc];
    }
    __syncthreads();
    #pragma unroll
    for (int k = 0; k < 16; k++){
      float4 av = *reinterpret_cast<const float4*>(&Asx[k][ty*4]);
      float4 bv = *reinterpret_cast<const float4*>(&Wsx[k][tx*4]);
      float a[4] = {av.x, av.y, av.z, av.w};
      float b2[4] = {bv.x, bv.y, bv.z, bv.w};
      #pragma unroll
      for (int i = 0; i < 4; i++)
        #pragma unroll
        for (int j = 0; j < 4; j++)
          acc[i][j] = fmaf(a[i], b2[j], acc[i][j]);
    }
    __syncthreads();
  }
  #pragma unroll
  for (int i = 0; i < 4; i++){
    const int r = row0 + ty*4 + i;
    #pragma unroll
    for (int j = 0; j < 4; j++){
      const int cn = col0 + tx*4 + j;
      float v = acc[i][j] + b[cn];
      g_h [(size_t)r*HIDD + cn] = v;
      g_hb[(size_t)r*HIDD + cn] = __float2bfloat16(v);
    }
  }
}

__global__ __launch_bounds__(256) void out_gemm(
    const float* __restrict__ W, const float* __restrict__ b,
    float* __restrict__ out)
{
  __shared__ __align__(16) float Asx[16][68];
  __shared__ __align__(16) float Wsx[16][68];
  const int tid = threadIdx.x;
  const int tx = tid & 15, ty = tid >> 4;
  const int row0 = blockIdx.y * 64, col0 = blockIdx.x * 64;
  const int lc = tid & 15, lr = tid >> 4;
  float acc[4][4] = {};
  for (int k0 = 0; k0 < HIDD; k0 += 16){
    #pragma unroll
    for (int i = 0; i < 4; i++){
      Asx[lc][lr + 16*i] = g_h[(size_t)(row0 + lr + 16*i)*HIDD + k0 + lc];
      Wsx[lc][lr + 16*i] = W[(size_t)(col0 + lr + 16*i)*HIDD + k0 + lc];
    }
    __syncthreads();
    #pragma unroll
    for (int k = 0; k < 16; k++){
      float4 av = *reinterpret_cast<const float4*>(&Asx[k][ty*4]);
      float4 bv = *reinterpret_cast<const float4*>(&Wsx[k][tx*4]);
      float a[4] = {av.x, av.y, av.z, av.w};
      float b2[4] = {bv.x, bv.y, bv.z, bv.w};
      #pragma unroll
      for (int i = 0; i < 4; i++)
        #pragma unroll
        for (int j = 0; j < 4; j++)
          acc[i][j] = fmaf(a[i], b2[j], acc[i][j]);
    }
    __syncthreads();
  }
  #pragma unroll
  for (int i = 0; i < 4; i++){
    const int r = row0 + ty*4 + i;
    #pragma unroll
    for (int j = 0; j < 4; j++){
      const int cn = col0 + tx*4 + j;
      out[(size_t)r*OUTD + cn] = acc[i][j] + b[cn];
    }
  }
}

// ---------------------------------------------------------------------------
// lam_s = exp(-exp(nu)) * (cos(exp(th)) + i sin(exp(th)))
// ---------------------------------------------------------------------------
__device__ __forceinline__ void lam_of(const float* __restrict__ nu_log,
                                       const float* __restrict__ th_log,
                                       int s, float& lr, float& li)
{
  float nu  = expf(nu_log[s]);
  float th  = expf(th_log[s]);
  float mag = expf(-nu);
  lr = mag * cosf(th);
  li = mag * sinf(th);
}

// Carry-only local scan over 64-token chunks (fp32).
__global__ __launch_bounds__(256) void scan_local(
    const float* __restrict__ nu_log, const float* __restrict__ th_log)
{
  const int blk = blockIdx.x;          // chunk 0..511
  const int s   = threadIdx.x;
  float lr, li; lam_of(nu_log, th_log, s, lr, li);
  float ar = 0.f, ai = 0.f;
  size_t base = (size_t)blk * CHUNK * 512 + s;
  for (int t = 0; t < CHUNK; t++){
    float br = g_bu[base + (size_t)t*512];
    float bi = g_bu[base + (size_t)t*512 + 256];
    float nr = fmaf(lr, ar, fmaf(-li, ai, br));
    float ni = fmaf(lr, ai, fmaf( li, ar, bi));
    ar = nr; ai = ni;
  }
  g_carry[(size_t)blk*512 + s]       = ar;
  g_carry[(size_t)blk*512 + 256 + s] = ai;
}

// Prefix accumulate + full local re-scan seeded with prefix; bf16 emit only.
__global__ __launch_bounds__(256) void scan_fix(
    const float* __restrict__ nu_log, const float* __restrict__ th_log)
{
  const int blk = blockIdx.x;
  const int c   = blk & (NCHUNK - 1);
  const int s   = threadIdx.x;
  float lr, li; lam_of(nu_log, th_log, s, lr, li);
  float cr = 0.f, ci = 0.f;
  if (c > 0){
    float Tr = lr, Ti = li;
    #pragma unroll
    for (int i = 0; i < 6; i++){ float nr = Tr*Tr - Ti*Ti; Ti = 2.f*Tr*Ti; Tr = nr; }
    const int bstart = blk - c;
    for (int j = 0; j < c; j++){
      float er = g_carry[(size_t)(bstart + j)*512 + s];
      float ei = g_carry[(size_t)(bstart + j)*512 + 256 + s];
      float nr = fmaf(Tr, cr, fmaf(-Ti, ci, er));
      float ni = fmaf(Tr, ci, fmaf( Ti, cr, ei));
      cr = nr; ci = ni;
    }
  }
  // inclusive scan with incoming state (cr,ci)
  float ar = cr, ai = ci;
  size_t base = (size_t)blk * CHUNK * 512 + s;
  for (int t = 0; t < CHUNK; t++){
    size_t o = base + (size_t)t*512;
    float br = g_bu[o], bi = g_bu[o + 256];
    float nr = fmaf(lr, ar, fmaf(-li, ai, br));
    float ni = fmaf(lr, ai, fmaf( li, ar, bi));
    ar = nr; ai = ni;
    g_bub[o]       = __float2bfloat16(ar);
    g_bub[o + 256] = __float2bfloat16(ai);
  }
}

// Pack B_norm for ALL layers -> bf16 (per layer 512 x 256)
__global__ __launch_bounds__(256) void pack_B(
    const float* __restrict__ Bre, const float* __restrict__ Bim,
    const float* __restrict__ gl)
{
  int idx = blockIdx.x * 256 + threadIdx.x;      // 0..NLAYERS*65536-1
  int l = idx >> 16, within = idx & 65535;
  int s = within >> 8;
  float g = expf(gl[l*STATE_D + s]);
  g_Bnb[(size_t)l*131072 + within]         = __float2bfloat16(Bre[idx] * g);
  g_Bnb[(size_t)l*131072 + 65536 + within] = __float2bfloat16(Bim[idx] * g);
}

// Pack Cw for ALL layers -> bf16 (per layer 256 x 512): [Cre | -Cim]
__global__ __launch_bounds__(256) void pack_C(
    const float* __restrict__ Cre, const float* __restrict__ Cim)
{
  int idx = blockIdx.x * 256 + threadIdx.x;      // 0..NLAYERS*65536-1
  int l = idx >> 16, within = idx & 65535;
  int h = within >> 8, s = within & 255;
  g_Cwb[(size_t)l*131072 + (size_t)h*512 + s]       = __float2bfloat16( Cre[idx]);
  g_Cwb[(size_t)l*131072 + (size_t)h*512 + 256 + s] = __float2bfloat16(-Cim[idx]);
}

// Straight fp32 -> bf16 weight convert into selected buffer
__global__ __launch_bounds__(256) void conv_bf16(
    const float* __restrict__ src, int dstSel, int n)
{
  int i = blockIdx.x * 256 + threadIdx.x;
  if (i < n) bufb(dstSel)[i] = __float2bfloat16(src[i]);
}

// ---------------------------------------------------------------------------
extern "C" void kernel_launch(void* const* d_in, const int* in_sizes, int n_in,
                              void* d_out, int out_size, void* d_ws, size_t ws_size,
                              hipStream_t stream)
{
  (void)d_ws; (void)ws_size; (void)out_size; (void)n_in; (void)in_sizes;
  const float* x      = (const float*)d_in[0];
  const float* emb_W  = (const float*)d_in[1];
  const float* emb_b  = (const float*)d_in[2];
  const float* nu_log = (const float*)d_in[3];
  const float* th_log = (const float*)d_in[4];
  const float* ga_log = (const float*)d_in[5];
  const float* B_re   = (const float*)d_in[6];
  const float* B_im   = (const float*)d_in[7];
  const float* C_re   = (const float*)d_in[8];
  const float* C_im   = (const float*)d_in[9];
  const float* Dv     = (const float*)d_in[10];
  const float* Wh     = (const float*)d_in[11];
  const float* bh     = (const float*)d_in[12];
  const float* Wo     = (const float*)d_in[13];
  const float* bo     = (const float*)d_in[14];
  const float* out_W  = (const float*)d_in[15];
  const float* out_b  = (const float*)d_in[16];

  const dim3 blk(256);

  // ---- all weight packing upfront (independent of activations) ----
  pack_B<<<dim3(NLAYERS*256), blk, 0, stream>>>(B_re, B_im, ga_log);
  pack_C<<<dim3(NLAYERS*256), blk, 0, stream>>>(C_re, C_im);
  conv_bf16<<<dim3(NLAYERS*1024), blk, 0, stream>>>(Wh, SB_WHB, NLAYERS*262144);
  conv_bf16<<<dim3(NLAYERS*1024), blk, 0, stream>>>(Wo, SB_WOB, NLAYERS*262144);

  // embed: h = x @ emb_W^T + emb_b  (fp32 GEMM + bf16 shadow)
  emb_gemm<<<dim3(HIDD/64, M_TOK/64), blk, 0, stream>>>(x, emb_W, emb_b);

  for (int l = 0; l < NLAYERS; l++){
    // Bu = h @ Bn^T   (32768 x 512 x 256) -> g_bu fp32   [2 col-groups]
    mfma_gemm<0, 0><<<dim3(2, M_TOK/128), blk, 0, stream>>>(
        SB_HB, HIDD, SB_BNB, l*131072, HIDD, SF_BU, -1, 512,
        nullptr, -1, 0, nullptr, HIDD);

    // chunked scan (fp32) + bf16 shadow
    scan_local<<<dim3(M_TOK/CHUNK), blk, 0, stream>>>(nu_log + l*STATE_D, th_log + l*STATE_D);
    scan_fix  <<<dim3(M_TOK/CHUNK), blk, 0, stream>>>(nu_log + l*STATE_D, th_log + l*STATE_D);

    // y = states @ Cw^T + D*h   (32768 x 256 x 512) -> g_y + g_yb  [1 col-group]
    mfma_gemm<0, 4><<<dim3(1, M_TOK/128), blk, 0, stream>>>(
        SB_BUB, 512, SB_CWB, l*131072, 512, SF_Y, SB_YB, HIDD,
        nullptr, SF_H, HIDD, Dv + l*HIDD, 512);

    // z = gelu(y @ Wh^T + bh)   (32768 x 1024 x 256) -> g_zb only  [4 col-groups]
    mfma_gemm<1, 1><<<dim3(4, M_TOK/128), blk, 0, stream>>>(
        SB_YB, HIDD, SB_WHB, l*262144, STATE_D, -1, SB_ZB, MLPD,
        bh + l*MLPD, -1, 0, nullptr, STATE_D);

    // h = z @ Wo^T + bo + y     (32768 x 256 x 1024) -> g_h + g_hb [1 col-group]
    mfma_gemm<0, 3><<<dim3(1, M_TOK/128), blk, 0, stream>>>(
        SB_ZB, MLPD, SB_WOB, l*262144, MLPD, SF_H, SB_HB, HIDD,
        bo + l*HIDD, SF_Y, HIDD, nullptr, MLPD);
  }

  // out = h @ out_W^T + out_b  (fp32 GEMM, fp32 store)
  out_gemm<<<dim3(OUTD/64, M_TOK/64), blk, 0, stream>>>(out_W, out_b, (float*)d_out);
}

// Round 6
// 1150.358 us; speedup vs baseline: 1.1115x; 1.1115x over previous
//
#include <hip/hip_runtime.h>
#include <hip/hip_bf16.h>
#include <math.h>

typedef __hip_bfloat16 bf16;
typedef __attribute__((ext_vector_type(8))) short bf16x8;   // 8 bf16 = 4 VGPR
typedef __attribute__((ext_vector_type(4))) float f32x4;    // MFMA acc

#define BATCH   16
#define SEQLEN  2048
#define INDIM   64
#define HIDD    256
#define STATE_D 256
#define MLPD    1024
#define OUTD    128
#define NLAYERS 4
#define M_TOK   (BATCH*SEQLEN)     // 32768 tokens
#define CHUNK   64
#define NCHUNK  (SEQLEN/CHUNK)     // 32 chunks per batch

// ---- fp32 masters (residual chain precision) -------------------------------
__device__ float g_h [(size_t)M_TOK*256];
__device__ float g_y [(size_t)M_TOK*256];
__device__ float g_bu[(size_t)M_TOK*512];
__device__ float g_carry[512*512];
// ---- bf16 shadows / packed weights (MFMA operands) -------------------------
__device__ bf16  g_hb [(size_t)M_TOK*256];
__device__ bf16  g_yb [(size_t)M_TOK*256];
__device__ bf16  g_bub[(size_t)M_TOK*512];
__device__ bf16  g_zb [(size_t)M_TOK*1024];
// per-layer packed weights (hoisted out of the layer loop)
__device__ bf16  g_Bnb[NLAYERS*512*256];    // B_norm: rows 0-255 re, 256-511 im
__device__ bf16  g_Cwb[NLAYERS*256*512];    // [Cre | -Cim]
__device__ bf16  g_Whb[NLAYERS*1024*256];
__device__ bf16  g_Wob[NLAYERS*256*1024];

#define SF_H  0
#define SF_Y  1
#define SF_BU 2
#define SB_HB  0
#define SB_YB  1
#define SB_BUB 2
#define SB_ZB  3
#define SB_BNB 4
#define SB_CWB 5
#define SB_WHB 6
#define SB_WOB 7

__device__ __forceinline__ float* buff(int sel){
  switch(sel){ case SF_H: return g_h; case SF_Y: return g_y; default: return g_bu; }
}
__device__ __forceinline__ bf16* bufb(int sel){
  switch(sel){
    case SB_HB:  return g_hb;  case SB_YB:  return g_yb;
    case SB_BUB: return g_bub; case SB_ZB:  return g_zb;
    case SB_BNB: return g_Bnb; case SB_CWB: return g_Cwb;
    case SB_WHB: return g_Whb; default:     return g_Wob; }
}

// async global->LDS, 16B per lane. LDS dest is wave-uniform base + lane*16.
__device__ __forceinline__ void gld_lds16(const void* g, void* l){
  __builtin_amdgcn_global_load_lds(
      (const __attribute__((address_space(1))) unsigned int*)g,
      (__attribute__((address_space(3))) unsigned int*)l, 16, 0, 0);
}

// Branch-free exact-GELU via Abramowitz-Stegun 7.1.26 erf (|err|<=1.5e-7,
// far below bf16 rounding). ~16 VALU, no divergence (verified R4: the
// 54%-VALUBusy erff dispatches left the top-5).
__device__ __forceinline__ float fast_gelu(float v){
  const float x  = v * 0.70710678118654752f;
  const float ax = fabsf(x);
  const float t  = __builtin_amdgcn_rcpf(fmaf(0.3275911f, ax, 1.0f));
  float p = fmaf(t, 1.061405429f, -1.453152027f);
  p = fmaf(t, p, 1.421413741f);
  p = fmaf(t, p, -0.284496736f);
  p = fmaf(t, p, 0.254829592f);
  p = p * t;
  const float e = __expf(-ax * ax);
  const float erf_ax = fmaf(-p, e, 1.0f);
  const float erf_x  = copysignf(erf_ax, x);
  return 0.5f * v * (1.0f + erf_x);
}

// ---------------------------------------------------------------------------
// MFMA GEMM: C[M,N] = act(A @ W^T + bias) (+res / +dscale*res)
// A: bf16 [M,K] lda;  W: bf16 [N,K] ldw (+wOff).
// 64x128 block tile, 4 waves (wave tile 32x64), BK=32, 2-deep LDS ring.
// REGIME (R1-R5 evidence): these GEMMs are latency-bound — perf tracks
// resident-wave count (z @2048 blocks = 286 TF vs Bu @1024 = 118 TF vs
// wide-tile @512 blocks/2-per-CU = 81 TF), while MfmaUtil/HBM%/conflicts
// stay low. So: small tile (24 KB LDS -> 5-6 blocks/CU) + doubled grids
// (1024-4096 blocks), keeping the verified-good R3 discipline:
//   iter t: vmcnt(3)->barrier  [tile t resident everywhere]
//           12x... 6x ds_read_b128 (cur) ; lgkm(0); sched_barrier; barrier
//           STAGE(buf[t&1], tile t+2)    [safe: all reads of buf done]
//           8x MFMA (setprio-wrapped)
// T2 source-side swizzle keeps ds_read conflict-free (verified 2.1M->0).
// XCD-chunked bijective blockIdx swizzle (kept from best-known config).
// FLAGS: 1=bias  2=add res  4=add dscale[n]*res.  ACT: 1=exact GELU (fast erf).
// ---------------------------------------------------------------------------
template<int ACT, int FLAGS>
__global__ __launch_bounds__(256, 4) void mfma_gemm(
    int aSel, int lda, int wSel, int wOff, int ldw,
    int oFSel, int oBSel, int ldc,
    const float* __restrict__ bias,
    int rSel, int ldres,
    const float* __restrict__ dscale,
    int K)
{
  const bf16* A = bufb(aSel);
  const bf16* W = bufb(wSel) + wOff;
  float* OF = (oFSel >= 0) ? buff(oFSel) : nullptr;
  bf16*  OB = (oBSel >= 0) ? bufb(oBSel) : nullptr;
  const float* res = (rSel >= 0) ? buff(rSel) : nullptr;

  __shared__ __align__(16) unsigned short As[2*64*32];    // 2 x 4 KB
  __shared__ __align__(16) unsigned short Ws[2*128*32];   // 2 x 8 KB

  // ---- XCD-chunked bijective blockIdx swizzle (m204 formula) ----
  const int gx = gridDim.x;
  const int nwg = gx * gridDim.y;
  const int orig = blockIdx.y * gx + blockIdx.x;
  const int q = nwg >> 3, r = nwg & 7;
  const int xcd = orig & 7, idx = orig >> 3;
  const int wg = (xcd < r ? xcd*(q+1) : r*(q+1) + (xcd-r)*q) + idx;
  const int bx = wg % gx, by = wg / gx;

  const int tid  = threadIdx.x;
  const int row0 = by * 64, col0 = bx * 128;
  const int lane = tid & 63;
  const int m16  = lane & 15, quad = lane >> 4;
  const int wv   = tid >> 6;
  const int wm   = (wv & 1) * 32, wn = (wv >> 1) * 64;

  // staging: wave w, lane l -> LDS row w*16 + (l>>2), slot (l&3).
  // Source k-group is XOR-swizzled by row ((r>>1)&3; consistent under r+=64).
  const int rlo = wv*16 + (lane >> 2);
  const int sg  = ((lane & 3) ^ ((rlo >> 1) & 3)) * 8;    // shorts
  const bf16* ga = &A[(size_t)(row0 + rlo)*lda + sg];
  const bf16* gw = &W[(size_t)(col0 + rlo)*ldw + sg];
  const size_t w64 = (size_t)64 * ldw;

  auto STAGE = [&](int bb, int k0){
    unsigned short* Ab = As + bb*2048;
    unsigned short* Wb = Ws + bb*4096;
    gld_lds16(ga + k0,       Ab + wv*512);
    gld_lds16(gw + k0,       Wb + wv*512);
    gld_lds16(gw + k0 + w64, Wb + 2048 + wv*512);
  };

  f32x4 acc[2][4] = {};
  const int nt = K >> 5;    // 8/16/32 for our shapes

  STAGE(0, 0); STAGE(1, 32);     // 6 vm loads/wave in flight

  for (int t = 0; t < nt; ++t){
    const int b = t & 1;
    // tile t resident when <= 3 younger loads outstanding
    if (t + 1 < nt) asm volatile("s_waitcnt vmcnt(3)" ::: "memory");
    else            asm volatile("s_waitcnt vmcnt(0)" ::: "memory");
    __builtin_amdgcn_s_barrier();            // all waves' portions resident

    const unsigned short* Ab = As + b*2048;
    const unsigned short* Wb = Ws + b*4096;
    bf16x8 af[2], wf[4];
    #pragma unroll
    for (int i = 0; i < 2; i++){
      const int rA = wm + 16*i + m16;
      af[i] = *reinterpret_cast<const bf16x8*>(&Ab[rA*32 + ((quad ^ ((rA>>1)&3))<<3)]);
    }
    #pragma unroll
    for (int j = 0; j < 4; j++){
      const int rW = wn + 16*j + m16;
      wf[j] = *reinterpret_cast<const bf16x8*>(&Wb[rW*32 + ((quad ^ ((rW>>1)&3))<<3)]);
    }
    asm volatile("s_waitcnt lgkmcnt(0)" ::: "memory");   // this wave's reads done
    __builtin_amdgcn_sched_barrier(0);                   // rule #18
    __builtin_amdgcn_s_barrier();                        // all waves done with buf b

    if (t + 2 < nt) STAGE(b, (t + 2) << 5);              // refill freed buffer

    __builtin_amdgcn_s_setprio(1);
    #pragma unroll
    for (int i = 0; i < 2; i++)
      #pragma unroll
      for (int j = 0; j < 4; j++)
        acc[i][j] = __builtin_amdgcn_mfma_f32_16x16x32_bf16(af[i], wf[j], acc[i][j], 0, 0, 0);
    __builtin_amdgcn_s_setprio(0);
  }

  // epilogue: C/D layout col=lane&15, row=quad*4+reg  (m89-verified)
  #pragma unroll
  for (int i = 0; i < 2; i++){
    #pragma unroll
    for (int j = 0; j < 4; j++){
      const int col = col0 + wn + 16*j + m16;
      #pragma unroll
      for (int r2 = 0; r2 < 4; r2++){
        const int row = row0 + wm + 16*i + quad*4 + r2;
        float v = acc[i][j][r2];
        if (FLAGS & 1) v += bias[col];
        if (ACT == 1)  v = fast_gelu(v);
        if (FLAGS & 2) v += res[(size_t)row*ldres + col];
        if (FLAGS & 4) v += dscale[col] * res[(size_t)row*ldres + col];
        const size_t o = (size_t)row*ldc + col;
        if (OF) OF[o] = v;
        if (OB) OB[o] = __float2bfloat16(v);
      }
    }
  }
}

// ---------------------------------------------------------------------------
// fp32 tiled GEMMs for the small ends (embed, out) — proven R12 structure.
// ---------------------------------------------------------------------------
__global__ __launch_bounds__(256) void emb_gemm(
    const float* __restrict__ x, const float* __restrict__ W,
    const float* __restrict__ b)
{
  __shared__ __align__(16) float Asx[16][68];
  __shared__ __align__(16) float Wsx[16][68];
  const int tid = threadIdx.x;
  const int tx = tid & 15, ty = tid >> 4;
  const int row0 = blockIdx.y * 64, col0 = blockIdx.x * 64;
  const int lc = tid & 15, lr = tid >> 4;
  float acc[4][4] = {};
  for (int k0 = 0; k0 < INDIM; k0 += 16){
    #pragma unroll
    for (int i = 0; i < 4; i++){
      Asx[lc][lr + 16*i] = x[(size_t)(row0 + lr + 16*i)*INDIM + k0 + lc];
      Wsx[lc][lr + 16*i] = W[(size_t)(col0 + lr + 16*i)*INDIM + k0 + lc];
    }
    __syncthreads();
    #pragma unroll
    for (int k = 0; k < 16; k++){
      float4 av = *reinterpret_cast<const float4*>(&Asx[k][ty*4]);
      float4 bv = *reinterpret_cast<const float4*>(&Wsx[k][tx*4]);
      float a[4] = {av.x, av.y, av.z, av.w};
      float b2[4] = {bv.x, bv.y, bv.z, bv.w};
      #pragma unroll
      for (int i = 0; i < 4; i++)
        #pragma unroll
        for (int j = 0; j < 4; j++)
          acc[i][j] = fmaf(a[i], b2[j], acc[i][j]);
    }
    __syncthreads();
  }
  #pragma unroll
  for (int i = 0; i < 4; i++){
    const int r = row0 + ty*4 + i;
    #pragma unroll
    for (int j = 0; j < 4; j++){
      const int cn = col0 + tx*4 + j;
      float v = acc[i][j] + b[cn];
      g_h [(size_t)r*HIDD + cn] = v;
      g_hb[(size_t)r*HIDD + cn] = __float2bfloat16(v);
    }
  }
}

__global__ __launch_bounds__(256) void out_gemm(
    const float* __restrict__ W, const float* __restrict__ b,
    float* __restrict__ out)
{
  __shared__ __align__(16) float Asx[16][68];
  __shared__ __align__(16) float Wsx[16][68];
  const int tid = threadIdx.x;
  const int tx = tid & 15, ty = tid >> 4;
  const int row0 = blockIdx.y * 64, col0 = blockIdx.x * 64;
  const int lc = tid & 15, lr = tid >> 4;
  float acc[4][4] = {};
  for (int k0 = 0; k0 < HIDD; k0 += 16){
    #pragma unroll
    for (int i = 0; i < 4; i++){
      Asx[lc][lr + 16*i] = g_h[(size_t)(row0 + lr + 16*i)*HIDD + k0 + lc];
      Wsx[lc][lr + 16*i] = W[(size_t)(col0 + lr + 16*i)*HIDD + k0 + lc];
    }
    __syncthreads();
    #pragma unroll
    for (int k = 0; k < 16; k++){
      float4 av = *reinterpret_cast<const float4*>(&Asx[k][ty*4]);
      float4 bv = *reinterpret_cast<const float4*>(&Wsx[k][tx*4]);
      float a[4] = {av.x, av.y, av.z, av.w};
      float b2[4] = {bv.x, bv.y, bv.z, bv.w};
      #pragma unroll
      for (int i = 0; i < 4; i++)
        #pragma unroll
        for (int j = 0; j < 4; j++)
          acc[i][j] = fmaf(a[i], b2[j], acc[i][j]);
    }
    __syncthreads();
  }
  #pragma unroll
  for (int i = 0; i < 4; i++){
    const int r = row0 + ty*4 + i;
    #pragma unroll
    for (int j = 0; j < 4; j++){
      const int cn = col0 + tx*4 + j;
      out[(size_t)r*OUTD + cn] = acc[i][j] + b[cn];
    }
  }
}

// ---------------------------------------------------------------------------
// lam_s = exp(-exp(nu)) * (cos(exp(th)) + i sin(exp(th)))
// ---------------------------------------------------------------------------
__device__ __forceinline__ void lam_of(const float* __restrict__ nu_log,
                                       const float* __restrict__ th_log,
                                       int s, float& lr, float& li)
{
  float nu  = expf(nu_log[s]);
  float th  = expf(th_log[s]);
  float mag = expf(-nu);
  lr = mag * cosf(th);
  li = mag * sinf(th);
}

// Carry-only local scan over 64-token chunks (fp32).
__global__ __launch_bounds__(256) void scan_local(
    const float* __restrict__ nu_log, const float* __restrict__ th_log)
{
  const int blk = blockIdx.x;          // chunk 0..511
  const int s   = threadIdx.x;
  float lr, li; lam_of(nu_log, th_log, s, lr, li);
  float ar = 0.f, ai = 0.f;
  size_t base = (size_t)blk * CHUNK * 512 + s;
  for (int t = 0; t < CHUNK; t++){
    float br = g_bu[base + (size_t)t*512];
    float bi = g_bu[base + (size_t)t*512 + 256];
    float nr = fmaf(lr, ar, fmaf(-li, ai, br));
    float ni = fmaf(lr, ai, fmaf( li, ar, bi));
    ar = nr; ai = ni;
  }
  g_carry[(size_t)blk*512 + s]       = ar;
  g_carry[(size_t)blk*512 + 256 + s] = ai;
}

// Prefix accumulate + full local re-scan seeded with prefix; bf16 emit only.
__global__ __launch_bounds__(256) void scan_fix(
    const float* __restrict__ nu_log, const float* __restrict__ th_log)
{
  const int blk = blockIdx.x;
  const int c   = blk & (NCHUNK - 1);
  const int s   = threadIdx.x;
  float lr, li; lam_of(nu_log, th_log, s, lr, li);
  float cr = 0.f, ci = 0.f;
  if (c > 0){
    float Tr = lr, Ti = li;
    #pragma unroll
    for (int i = 0; i < 6; i++){ float nr = Tr*Tr - Ti*Ti; Ti = 2.f*Tr*Ti; Tr = nr; }
    const int bstart = blk - c;
    for (int j = 0; j < c; j++){
      float er = g_carry[(size_t)(bstart + j)*512 + s];
      float ei = g_carry[(size_t)(bstart + j)*512 + 256 + s];
      float nr = fmaf(Tr, cr, fmaf(-Ti, ci, er));
      float ni = fmaf(Tr, ci, fmaf( Ti, cr, ei));
      cr = nr; ci = ni;
    }
  }
  // inclusive scan with incoming state (cr,ci)
  float ar = cr, ai = ci;
  size_t base = (size_t)blk * CHUNK * 512 + s;
  for (int t = 0; t < CHUNK; t++){
    size_t o = base + (size_t)t*512;
    float br = g_bu[o], bi = g_bu[o + 256];
    float nr = fmaf(lr, ar, fmaf(-li, ai, br));
    float ni = fmaf(lr, ai, fmaf( li, ar, bi));
    ar = nr; ai = ni;
    g_bub[o]       = __float2bfloat16(ar);
    g_bub[o + 256] = __float2bfloat16(ai);
  }
}

// Pack B_norm for ALL layers -> bf16 (per layer 512 x 256)
__global__ __launch_bounds__(256) void pack_B(
    const float* __restrict__ Bre, const float* __restrict__ Bim,
    const float* __restrict__ gl)
{
  int idx = blockIdx.x * 256 + threadIdx.x;      // 0..NLAYERS*65536-1
  int l = idx >> 16, within = idx & 65535;
  int s = within >> 8;
  float g = expf(gl[l*STATE_D + s]);
  g_Bnb[(size_t)l*131072 + within]         = __float2bfloat16(Bre[idx] * g);
  g_Bnb[(size_t)l*131072 + 65536 + within] = __float2bfloat16(Bim[idx] * g);
}

// Pack Cw for ALL layers -> bf16 (per layer 256 x 512): [Cre | -Cim]
__global__ __launch_bounds__(256) void pack_C(
    const float* __restrict__ Cre, const float* __restrict__ Cim)
{
  int idx = blockIdx.x * 256 + threadIdx.x;      // 0..NLAYERS*65536-1
  int l = idx >> 16, within = idx & 65535;
  int h = within >> 8, s = within & 255;
  g_Cwb[(size_t)l*131072 + (size_t)h*512 + s]       = __float2bfloat16( Cre[idx]);
  g_Cwb[(size_t)l*131072 + (size_t)h*512 + 256 + s] = __float2bfloat16(-Cim[idx]);
}

// Straight fp32 -> bf16 weight convert into selected buffer
__global__ __launch_bounds__(256) void conv_bf16(
    const float* __restrict__ src, int dstSel, int n)
{
  int i = blockIdx.x * 256 + threadIdx.x;
  if (i < n) bufb(dstSel)[i] = __float2bfloat16(src[i]);
}

// ---------------------------------------------------------------------------
extern "C" void kernel_launch(void* const* d_in, const int* in_sizes, int n_in,
                              void* d_out, int out_size, void* d_ws, size_t ws_size,
                              hipStream_t stream)
{
  (void)d_ws; (void)ws_size; (void)out_size; (void)n_in; (void)in_sizes;
  const float* x      = (const float*)d_in[0];
  const float* emb_W  = (const float*)d_in[1];
  const float* emb_b  = (const float*)d_in[2];
  const float* nu_log = (const float*)d_in[3];
  const float* th_log = (const float*)d_in[4];
  const float* ga_log = (const float*)d_in[5];
  const float* B_re   = (const float*)d_in[6];
  const float* B_im   = (const float*)d_in[7];
  const float* C_re   = (const float*)d_in[8];
  const float* C_im   = (const float*)d_in[9];
  const float* Dv     = (const float*)d_in[10];
  const float* Wh     = (const float*)d_in[11];
  const float* bh     = (const float*)d_in[12];
  const float* Wo     = (const float*)d_in[13];
  const float* bo     = (const float*)d_in[14];
  const float* out_W  = (const float*)d_in[15];
  const float* out_b  = (const float*)d_in[16];

  const dim3 blk(256);

  // ---- all weight packing upfront (independent of activations) ----
  pack_B<<<dim3(NLAYERS*256), blk, 0, stream>>>(B_re, B_im, ga_log);
  pack_C<<<dim3(NLAYERS*256), blk, 0, stream>>>(C_re, C_im);
  conv_bf16<<<dim3(NLAYERS*1024), blk, 0, stream>>>(Wh, SB_WHB, NLAYERS*262144);
  conv_bf16<<<dim3(NLAYERS*1024), blk, 0, stream>>>(Wo, SB_WOB, NLAYERS*262144);

  // embed: h = x @ emb_W^T + emb_b  (fp32 GEMM + bf16 shadow)
  emb_gemm<<<dim3(HIDD/64, M_TOK/64), blk, 0, stream>>>(x, emb_W, emb_b);

  for (int l = 0; l < NLAYERS; l++){
    // Bu = h @ Bn^T   (32768 x 512 x 256) -> g_bu fp32   [2048 blocks]
    mfma_gemm<0, 0><<<dim3(4, M_TOK/64), blk, 0, stream>>>(
        SB_HB, HIDD, SB_BNB, l*131072, HIDD, SF_BU, -1, 512,
        nullptr, -1, 0, nullptr, HIDD);

    // chunked scan (fp32) + bf16 shadow
    scan_local<<<dim3(M_TOK/CHUNK), blk, 0, stream>>>(nu_log + l*STATE_D, th_log + l*STATE_D);
    scan_fix  <<<dim3(M_TOK/CHUNK), blk, 0, stream>>>(nu_log + l*STATE_D, th_log + l*STATE_D);

    // y = states @ Cw^T + D*h   (32768 x 256 x 512) -> g_y + g_yb  [1024 blocks]
    mfma_gemm<0, 4><<<dim3(2, M_TOK/64), blk, 0, stream>>>(
        SB_BUB, 512, SB_CWB, l*131072, 512, SF_Y, SB_YB, HIDD,
        nullptr, SF_H, HIDD, Dv + l*HIDD, 512);

    // z = gelu(y @ Wh^T + bh)   (32768 x 1024 x 256) -> g_zb only  [4096 blocks]
    mfma_gemm<1, 1><<<dim3(8, M_TOK/64), blk, 0, stream>>>(
        SB_YB, HIDD, SB_WHB, l*262144, STATE_D, -1, SB_ZB, MLPD,
        bh + l*MLPD, -1, 0, nullptr, STATE_D);

    // h = z @ Wo^T + bo + y     (32768 x 256 x 1024) -> g_h + g_hb [1024 blocks]
    mfma_gemm<0, 3><<<dim3(2, M_TOK/64), blk, 0, stream>>>(
        SB_ZB, MLPD, SB_WOB, l*262144, MLPD, SF_H, SB_HB, HIDD,
        bo + l*HIDD, SF_Y, HIDD, nullptr, MLPD);
  }

  // out = h @ out_W^T + out_b  (fp32 GEMM, fp32 store)
  out_gemm<<<dim3(OUTD/64, M_TOK/64), blk, 0, stream>>>(out_W, out_b, (float*)d_out);
}

// Round 7
// 899.046 us; speedup vs baseline: 1.4221x; 1.2795x over previous
//
#include <hip/hip_runtime.h>
#include <hip/hip_bf16.h>
#include <math.h>

typedef __hip_bfloat16 bf16;
typedef __attribute__((ext_vector_type(8))) short bf16x8;   // 8 bf16 = 4 VGPR
typedef __attribute__((ext_vector_type(4))) float f32x4;    // MFMA acc

#define BATCH   16
#define SEQLEN  2048
#define INDIM   64
#define HIDD    256
#define STATE_D 256
#define MLPD    1024
#define OUTD    128
#define NLAYERS 4
#define M_TOK   (BATCH*SEQLEN)     // 32768 tokens
#define CHUNK   64
#define NCHUNK  (SEQLEN/CHUNK)     // 32 chunks per batch

// ---- ALL-BF16 activation chain (R6 traffic analysis: fp32 masters were the
// dominant byte stream; GEMM inputs were already bf16 so storage rounding is
// second-order vs existing bf16-MFMA error) --------------------------------
__device__ float g_carry[512*512];          // fp32 scan carries (tiny)
__device__ bf16  g_hb [(size_t)M_TOK*256];
__device__ bf16  g_yb [(size_t)M_TOK*256];
__device__ bf16  g_bub[(size_t)M_TOK*512];  // raw Bu, then scan states (in place)
__device__ bf16  g_zb [(size_t)M_TOK*1024];
// per-layer packed weights (hoisted out of the layer loop)
__device__ bf16  g_Bnb[NLAYERS*512*256];    // B_norm: rows 0-255 re, 256-511 im
__device__ bf16  g_Cwb[NLAYERS*256*512];    // [Cre | -Cim]
__device__ bf16  g_Whb[NLAYERS*1024*256];
__device__ bf16  g_Wob[NLAYERS*256*1024];

#define SB_HB  0
#define SB_YB  1
#define SB_BUB 2
#define SB_ZB  3
#define SB_BNB 4
#define SB_CWB 5
#define SB_WHB 6
#define SB_WOB 7

__device__ __forceinline__ bf16* bufb(int sel){
  switch(sel){
    case SB_HB:  return g_hb;  case SB_YB:  return g_yb;
    case SB_BUB: return g_bub; case SB_ZB:  return g_zb;
    case SB_BNB: return g_Bnb; case SB_CWB: return g_Cwb;
    case SB_WHB: return g_Whb; default:     return g_Wob; }
}

// async global->LDS, 16B per lane. LDS dest is wave-uniform base + lane*16.
__device__ __forceinline__ void gld_lds16(const void* g, void* l){
  __builtin_amdgcn_global_load_lds(
      (const __attribute__((address_space(1))) unsigned int*)g,
      (__attribute__((address_space(3))) unsigned int*)l, 16, 0, 0);
}

// Branch-free exact-GELU via Abramowitz-Stegun 7.1.26 erf (|err|<=1.5e-7).
// Verified R4: removed the 54%-VALUBusy erff dispatches.
__device__ __forceinline__ float fast_gelu(float v){
  const float x  = v * 0.70710678118654752f;
  const float ax = fabsf(x);
  const float t  = __builtin_amdgcn_rcpf(fmaf(0.3275911f, ax, 1.0f));
  float p = fmaf(t, 1.061405429f, -1.453152027f);
  p = fmaf(t, p, 1.421413741f);
  p = fmaf(t, p, -0.284496736f);
  p = fmaf(t, p, 0.254829592f);
  p = p * t;
  const float e = __expf(-ax * ax);
  const float erf_ax = fmaf(-p, e, 1.0f);
  const float erf_x  = copysignf(erf_ax, x);
  return 0.5f * v * (1.0f + erf_x);
}

// ---------------------------------------------------------------------------
// MFMA GEMM: C[M,N] = act(A @ W^T + bias) (+res / +dscale*res), bf16 in/out.
// 64x128 block tile, 4 waves (wave tile 32x64), BK=32, 2-deep LDS ring,
// counted vmcnt, one stage per freed buffer (R6-verified discipline, passed).
// T2 source-side swizzle: ds_read conflict-free (verified 2.1M -> 0).
// XCD-chunked bijective blockIdx swizzle. launch_bounds(256,6): 24KB LDS
// allows 6 blocks/CU; R6 measured 36% occupancy at (256,4) — raise the cap.
// FLAGS: 1=bias  2=+res(bf16)  4=+dscale[n]*res(bf16).  ACT: 1=GELU.
// ---------------------------------------------------------------------------
template<int ACT, int FLAGS>
__global__ __launch_bounds__(256, 6) void mfma_gemm(
    int aSel, int lda, int wSel, int wOff, int ldw,
    int oSel, int ldc,
    const float* __restrict__ bias,
    int rSel, int ldres,
    const float* __restrict__ dscale,
    int K)
{
  const bf16* A = bufb(aSel);
  const bf16* W = bufb(wSel) + wOff;
  bf16* OB = bufb(oSel);
  const bf16* res = (rSel >= 0) ? bufb(rSel) : nullptr;

  __shared__ __align__(16) unsigned short As[2*64*32];    // 2 x 4 KB
  __shared__ __align__(16) unsigned short Ws[2*128*32];   // 2 x 8 KB

  // ---- XCD-chunked bijective blockIdx swizzle (m204 formula) ----
  const int gx = gridDim.x;
  const int nwg = gx * gridDim.y;
  const int orig = blockIdx.y * gx + blockIdx.x;
  const int q = nwg >> 3, r = nwg & 7;
  const int xcd = orig & 7, idx = orig >> 3;
  const int wg = (xcd < r ? xcd*(q+1) : r*(q+1) + (xcd-r)*q) + idx;
  const int bx = wg % gx, by = wg / gx;

  const int tid  = threadIdx.x;
  const int row0 = by * 64, col0 = bx * 128;
  const int lane = tid & 63;
  const int m16  = lane & 15, quad = lane >> 4;
  const int wv   = tid >> 6;
  const int wm   = (wv & 1) * 32, wn = (wv >> 1) * 64;

  // staging: wave w, lane l -> LDS row w*16 + (l>>2), slot (l&3).
  // Source k-group is XOR-swizzled by row ((r>>1)&3; consistent under r+=64).
  const int rlo = wv*16 + (lane >> 2);
  const int sg  = ((lane & 3) ^ ((rlo >> 1) & 3)) * 8;    // shorts
  const bf16* ga = &A[(size_t)(row0 + rlo)*lda + sg];
  const bf16* gw = &W[(size_t)(col0 + rlo)*ldw + sg];
  const size_t w64 = (size_t)64 * ldw;

  auto STAGE = [&](int bb, int k0){
    unsigned short* Ab = As + bb*2048;
    unsigned short* Wb = Ws + bb*4096;
    gld_lds16(ga + k0,       Ab + wv*512);
    gld_lds16(gw + k0,       Wb + wv*512);
    gld_lds16(gw + k0 + w64, Wb + 2048 + wv*512);
  };

  f32x4 acc[2][4] = {};
  const int nt = K >> 5;    // 8/16/32 for our shapes

  STAGE(0, 0); STAGE(1, 32);     // 6 vm loads/wave in flight

  for (int t = 0; t < nt; ++t){
    const int b = t & 1;
    // tile t resident when <= 3 younger loads outstanding
    if (t + 1 < nt) asm volatile("s_waitcnt vmcnt(3)" ::: "memory");
    else            asm volatile("s_waitcnt vmcnt(0)" ::: "memory");
    __builtin_amdgcn_s_barrier();            // all waves' portions resident

    const unsigned short* Ab = As + b*2048;
    const unsigned short* Wb = Ws + b*4096;
    bf16x8 af[2], wf[4];
    #pragma unroll
    for (int i = 0; i < 2; i++){
      const int rA = wm + 16*i + m16;
      af[i] = *reinterpret_cast<const bf16x8*>(&Ab[rA*32 + ((quad ^ ((rA>>1)&3))<<3)]);
    }
    #pragma unroll
    for (int j = 0; j < 4; j++){
      const int rW = wn + 16*j + m16;
      wf[j] = *reinterpret_cast<const bf16x8*>(&Wb[rW*32 + ((quad ^ ((rW>>1)&3))<<3)]);
    }
    asm volatile("s_waitcnt lgkmcnt(0)" ::: "memory");   // this wave's reads done
    __builtin_amdgcn_sched_barrier(0);                   // rule #18
    __builtin_amdgcn_s_barrier();                        // all waves done with buf b

    if (t + 2 < nt) STAGE(b, (t + 2) << 5);              // refill freed buffer

    __builtin_amdgcn_s_setprio(1);
    #pragma unroll
    for (int i = 0; i < 2; i++)
      #pragma unroll
      for (int j = 0; j < 4; j++)
        acc[i][j] = __builtin_amdgcn_mfma_f32_16x16x32_bf16(af[i], wf[j], acc[i][j], 0, 0, 0);
    __builtin_amdgcn_s_setprio(0);
  }

  // epilogue: C/D layout col=lane&15, row=quad*4+reg  (m89-verified)
  #pragma unroll
  for (int i = 0; i < 2; i++){
    #pragma unroll
    for (int j = 0; j < 4; j++){
      const int col = col0 + wn + 16*j + m16;
      #pragma unroll
      for (int r2 = 0; r2 < 4; r2++){
        const int row = row0 + wm + 16*i + quad*4 + r2;
        float v = acc[i][j][r2];
        if (FLAGS & 1) v += bias[col];
        if (ACT == 1)  v = fast_gelu(v);
        if (FLAGS & 2) v += __bfloat162float(res[(size_t)row*ldres + col]);
        if (FLAGS & 4) v += dscale[col] * __bfloat162float(res[(size_t)row*ldres + col]);
        OB[(size_t)row*ldc + col] = __float2bfloat16(v);
      }
    }
  }
}

// ---------------------------------------------------------------------------
// fp32 tiled GEMMs for the small ends (embed, out) — proven R12 structure.
// ---------------------------------------------------------------------------
__global__ __launch_bounds__(256) void emb_gemm(
    const float* __restrict__ x, const float* __restrict__ W,
    const float* __restrict__ b)
{
  __shared__ __align__(16) float Asx[16][68];
  __shared__ __align__(16) float Wsx[16][68];
  const int tid = threadIdx.x;
  const int tx = tid & 15, ty = tid >> 4;
  const int row0 = blockIdx.y * 64, col0 = blockIdx.x * 64;
  const int lc = tid & 15, lr = tid >> 4;
  float acc[4][4] = {};
  for (int k0 = 0; k0 < INDIM; k0 += 16){
    #pragma unroll
    for (int i = 0; i < 4; i++){
      Asx[lc][lr + 16*i] = x[(size_t)(row0 + lr + 16*i)*INDIM + k0 + lc];
      Wsx[lc][lr + 16*i] = W[(size_t)(col0 + lr + 16*i)*INDIM + k0 + lc];
    }
    __syncthreads();
    #pragma unroll
    for (int k = 0; k < 16; k++){
      float4 av = *reinterpret_cast<const float4*>(&Asx[k][ty*4]);
      float4 bv = *reinterpret_cast<const float4*>(&Wsx[k][tx*4]);
      float a[4] = {av.x, av.y, av.z, av.w};
      float b2[4] = {bv.x, bv.y, bv.z, bv.w};
      #pragma unroll
      for (int i = 0; i < 4; i++)
        #pragma unroll
        for (int j = 0; j < 4; j++)
          acc[i][j] = fmaf(a[i], b2[j], acc[i][j]);
    }
    __syncthreads();
  }
  #pragma unroll
  for (int i = 0; i < 4; i++){
    const int r = row0 + ty*4 + i;
    #pragma unroll
    for (int j = 0; j < 4; j++){
      const int cn = col0 + tx*4 + j;
      g_hb[(size_t)r*HIDD + cn] = __float2bfloat16(acc[i][j] + b[cn]);
    }
  }
}

__global__ __launch_bounds__(256) void out_gemm(
    const float* __restrict__ W, const float* __restrict__ b,
    float* __restrict__ out)
{
  __shared__ __align__(16) float Asx[16][68];
  __shared__ __align__(16) float Wsx[16][68];
  const int tid = threadIdx.x;
  const int tx = tid & 15, ty = tid >> 4;
  const int row0 = blockIdx.y * 64, col0 = blockIdx.x * 64;
  const int lc = tid & 15, lr = tid >> 4;
  float acc[4][4] = {};
  for (int k0 = 0; k0 < HIDD; k0 += 16){
    #pragma unroll
    for (int i = 0; i < 4; i++){
      Asx[lc][lr + 16*i] = __bfloat162float(g_hb[(size_t)(row0 + lr + 16*i)*HIDD + k0 + lc]);
      Wsx[lc][lr + 16*i] = W[(size_t)(col0 + lr + 16*i)*HIDD + k0 + lc];
    }
    __syncthreads();
    #pragma unroll
    for (int k = 0; k < 16; k++){
      float4 av = *reinterpret_cast<const float4*>(&Asx[k][ty*4]);
      float4 bv = *reinterpret_cast<const float4*>(&Wsx[k][tx*4]);
      float a[4] = {av.x, av.y, av.z, av.w};
      float b2[4] = {bv.x, bv.y, bv.z, bv.w};
      #pragma unroll
      for (int i = 0; i < 4; i++)
        #pragma unroll
        for (int j = 0; j < 4; j++)
          acc[i][j] = fmaf(a[i], b2[j], acc[i][j]);
    }
    __syncthreads();
  }
  #pragma unroll
  for (int i = 0; i < 4; i++){
    const int r = row0 + ty*4 + i;
    #pragma unroll
    for (int j = 0; j < 4; j++){
      const int cn = col0 + tx*4 + j;
      out[(size_t)r*OUTD + cn] = acc[i][j] + b[cn];
    }
  }
}

// ---------------------------------------------------------------------------
// lam_s = exp(-exp(nu)) * (cos(exp(th)) + i sin(exp(th)))
// ---------------------------------------------------------------------------
__device__ __forceinline__ void lam_of(const float* __restrict__ nu_log,
                                       const float* __restrict__ th_log,
                                       int s, float& lr, float& li)
{
  float nu  = expf(nu_log[s]);
  float th  = expf(th_log[s]);
  float mag = expf(-nu);
  lr = mag * cosf(th);
  li = mag * sinf(th);
}

// Carry-only local scan over 64-token chunks. Reads raw Bu (bf16), fp32 math.
__global__ __launch_bounds__(256) void scan_local(
    const float* __restrict__ nu_log, const float* __restrict__ th_log)
{
  const int blk = blockIdx.x;          // chunk 0..511
  const int s   = threadIdx.x;
  float lr, li; lam_of(nu_log, th_log, s, lr, li);
  float ar = 0.f, ai = 0.f;
  size_t base = (size_t)blk * CHUNK * 512 + s;
  for (int t = 0; t < CHUNK; t++){
    float br = __bfloat162float(g_bub[base + (size_t)t*512]);
    float bi = __bfloat162float(g_bub[base + (size_t)t*512 + 256]);
    float nr = fmaf(lr, ar, fmaf(-li, ai, br));
    float ni = fmaf(lr, ai, fmaf( li, ar, bi));
    ar = nr; ai = ni;
  }
  g_carry[(size_t)blk*512 + s]       = ar;
  g_carry[(size_t)blk*512 + 256 + s] = ai;
}

// Prefix accumulate + local re-scan seeded with prefix; overwrites g_bub
// in place with scan states (each element read once then written).
__global__ __launch_bounds__(256) void scan_fix(
    const float* __restrict__ nu_log, const float* __restrict__ th_log)
{
  const int blk = blockIdx.x;
  const int c   = blk & (NCHUNK - 1);
  const int s   = threadIdx.x;
  float lr, li; lam_of(nu_log, th_log, s, lr, li);
  float cr = 0.f, ci = 0.f;
  if (c > 0){
    float Tr = lr, Ti = li;
    #pragma unroll
    for (int i = 0; i < 6; i++){ float nr = Tr*Tr - Ti*Ti; Ti = 2.f*Tr*Ti; Tr = nr; }
    const int bstart = blk - c;
    for (int j = 0; j < c; j++){
      float er = g_carry[(size_t)(bstart + j)*512 + s];
      float ei = g_carry[(size_t)(bstart + j)*512 + 256 + s];
      float nr = fmaf(Tr, cr, fmaf(-Ti, ci, er));
      float ni = fmaf(Tr, ci, fmaf( Ti, cr, ei));
      cr = nr; ci = ni;
    }
  }
  // inclusive scan with incoming state (cr,ci)
  float ar = cr, ai = ci;
  size_t base = (size_t)blk * CHUNK * 512 + s;
  for (int t = 0; t < CHUNK; t++){
    size_t o = base + (size_t)t*512;
    float br = __bfloat162float(g_bub[o]);
    float bi = __bfloat162float(g_bub[o + 256]);
    float nr = fmaf(lr, ar, fmaf(-li, ai, br));
    float ni = fmaf(lr, ai, fmaf( li, ar, bi));
    ar = nr; ai = ni;
    g_bub[o]       = __float2bfloat16(ar);
    g_bub[o + 256] = __float2bfloat16(ai);
  }
}

// Pack B_norm for ALL layers -> bf16 (per layer 512 x 256)
__global__ __launch_bounds__(256) void pack_B(
    const float* __restrict__ Bre, const float* __restrict__ Bim,
    const float* __restrict__ gl)
{
  int idx = blockIdx.x * 256 + threadIdx.x;      // 0..NLAYERS*65536-1
  int l = idx >> 16, within = idx & 65535;
  int s = within >> 8;
  float g = expf(gl[l*STATE_D + s]);
  g_Bnb[(size_t)l*131072 + within]         = __float2bfloat16(Bre[idx] * g);
  g_Bnb[(size_t)l*131072 + 65536 + within] = __float2bfloat16(Bim[idx] * g);
}

// Pack Cw for ALL layers -> bf16 (per layer 256 x 512): [Cre | -Cim]
__global__ __launch_bounds__(256) void pack_C(
    const float* __restrict__ Cre, const float* __restrict__ Cim)
{
  int idx = blockIdx.x * 256 + threadIdx.x;      // 0..NLAYERS*65536-1
  int l = idx >> 16, within = idx & 65535;
  int h = within >> 8, s = within & 255;
  g_Cwb[(size_t)l*131072 + (size_t)h*512 + s]       = __float2bfloat16( Cre[idx]);
  g_Cwb[(size_t)l*131072 + (size_t)h*512 + 256 + s] = __float2bfloat16(-Cim[idx]);
}

// Straight fp32 -> bf16 weight convert into selected buffer
__global__ __launch_bounds__(256) void conv_bf16(
    const float* __restrict__ src, int dstSel, int n)
{
  int i = blockIdx.x * 256 + threadIdx.x;
  if (i < n) bufb(dstSel)[i] = __float2bfloat16(src[i]);
}

// ---------------------------------------------------------------------------
extern "C" void kernel_launch(void* const* d_in, const int* in_sizes, int n_in,
                              void* d_out, int out_size, void* d_ws, size_t ws_size,
                              hipStream_t stream)
{
  (void)d_ws; (void)ws_size; (void)out_size; (void)n_in; (void)in_sizes;
  const float* x      = (const float*)d_in[0];
  const float* emb_W  = (const float*)d_in[1];
  const float* emb_b  = (const float*)d_in[2];
  const float* nu_log = (const float*)d_in[3];
  const float* th_log = (const float*)d_in[4];
  const float* ga_log = (const float*)d_in[5];
  const float* B_re   = (const float*)d_in[6];
  const float* B_im   = (const float*)d_in[7];
  const float* C_re   = (const float*)d_in[8];
  const float* C_im   = (const float*)d_in[9];
  const float* Dv     = (const float*)d_in[10];
  const float* Wh     = (const float*)d_in[11];
  const float* bh     = (const float*)d_in[12];
  const float* Wo     = (const float*)d_in[13];
  const float* bo     = (const float*)d_in[14];
  const float* out_W  = (const float*)d_in[15];
  const float* out_b  = (const float*)d_in[16];

  const dim3 blk(256);

  // ---- all weight packing upfront (independent of activations) ----
  pack_B<<<dim3(NLAYERS*256), blk, 0, stream>>>(B_re, B_im, ga_log);
  pack_C<<<dim3(NLAYERS*256), blk, 0, stream>>>(C_re, C_im);
  conv_bf16<<<dim3(NLAYERS*1024), blk, 0, stream>>>(Wh, SB_WHB, NLAYERS*262144);
  conv_bf16<<<dim3(NLAYERS*1024), blk, 0, stream>>>(Wo, SB_WOB, NLAYERS*262144);

  // embed: h = x @ emb_W^T + emb_b  -> g_hb (bf16 only)
  emb_gemm<<<dim3(HIDD/64, M_TOK/64), blk, 0, stream>>>(x, emb_W, emb_b);

  for (int l = 0; l < NLAYERS; l++){
    // Bu = h @ Bn^T   (32768 x 512 x 256) -> g_bub bf16   [2048 blocks]
    mfma_gemm<0, 0><<<dim3(4, M_TOK/64), blk, 0, stream>>>(
        SB_HB, HIDD, SB_BNB, l*131072, HIDD, SB_BUB, 512,
        nullptr, -1, 0, nullptr, HIDD);

    // chunked scan (fp32 in registers, bf16 in memory, in-place states)
    scan_local<<<dim3(M_TOK/CHUNK), blk, 0, stream>>>(nu_log + l*STATE_D, th_log + l*STATE_D);
    scan_fix  <<<dim3(M_TOK/CHUNK), blk, 0, stream>>>(nu_log + l*STATE_D, th_log + l*STATE_D);

    // y = states @ Cw^T + D*h   (32768 x 256 x 512) -> g_yb  [1024 blocks]
    mfma_gemm<0, 4><<<dim3(2, M_TOK/64), blk, 0, stream>>>(
        SB_BUB, 512, SB_CWB, l*131072, 512, SB_YB, HIDD,
        nullptr, SB_HB, HIDD, Dv + l*HIDD, 512);

    // z = gelu(y @ Wh^T + bh)   (32768 x 1024 x 256) -> g_zb  [4096 blocks]
    mfma_gemm<1, 1><<<dim3(8, M_TOK/64), blk, 0, stream>>>(
        SB_YB, HIDD, SB_WHB, l*262144, STATE_D, SB_ZB, MLPD,
        bh + l*MLPD, -1, 0, nullptr, STATE_D);

    // h = z @ Wo^T + bo + y     (32768 x 256 x 1024) -> g_hb  [1024 blocks]
    mfma_gemm<0, 3><<<dim3(2, M_TOK/64), blk, 0, stream>>>(
        SB_ZB, MLPD, SB_WOB, l*262144, MLPD, SB_HB, HIDD,
        bo + l*HIDD, SB_YB, HIDD, nullptr, MLPD);
  }

  // out = h @ out_W^T + out_b  (fp32 GEMM reading bf16 A, fp32 store)
  out_gemm<<<dim3(OUTD/64, M_TOK/64), blk, 0, stream>>>(out_W, out_b, (float*)d_out);
}

// Round 8
// 855.157 us; speedup vs baseline: 1.4951x; 1.0513x over previous
//
#include <hip/hip_runtime.h>
#include <hip/hip_bf16.h>
#include <math.h>

typedef __hip_bfloat16 bf16;
typedef __attribute__((ext_vector_type(8))) short bf16x8;   // 8 bf16 = 4 VGPR
typedef __attribute__((ext_vector_type(4))) float f32x4;    // MFMA acc

#define BATCH   16
#define SEQLEN  2048
#define INDIM   64
#define HIDD    256
#define STATE_D 256
#define MLPD    1024
#define OUTD    128
#define NLAYERS 4
#define M_TOK   (BATCH*SEQLEN)     // 32768 tokens
#define CHUNK   64
#define NCHUNK  (SEQLEN/CHUNK)     // 32 chunks per batch

// ---- ALL-BF16 activation chain (R7-verified: fp32 masters were the dominant
// byte stream; storage rounding second-order vs bf16-MFMA error) ------------
__device__ float g_carry[512*512];          // fp32 scan carries (tiny)
__device__ bf16  g_hb [(size_t)M_TOK*256];
__device__ bf16  g_yb [(size_t)M_TOK*256];
__device__ bf16  g_bub[(size_t)M_TOK*512];  // raw Bu, then scan states (in place)
__device__ bf16  g_zb [(size_t)M_TOK*1024];
// per-layer packed weights (hoisted out of the layer loop)
__device__ bf16  g_Bnb[NLAYERS*512*256];    // B_norm: rows 0-255 re, 256-511 im
__device__ bf16  g_Cwb[NLAYERS*256*512];    // [Cre | -Cim]
__device__ bf16  g_Whb[NLAYERS*1024*256];
__device__ bf16  g_Wob[NLAYERS*256*1024];

#define SB_HB  0
#define SB_YB  1
#define SB_BUB 2
#define SB_ZB  3
#define SB_BNB 4
#define SB_CWB 5
#define SB_WHB 6
#define SB_WOB 7

__device__ __forceinline__ bf16* bufb(int sel){
  switch(sel){
    case SB_HB:  return g_hb;  case SB_YB:  return g_yb;
    case SB_BUB: return g_bub; case SB_ZB:  return g_zb;
    case SB_BNB: return g_Bnb; case SB_CWB: return g_Cwb;
    case SB_WHB: return g_Whb; default:     return g_Wob; }
}

// async global->LDS, 16B per lane. LDS dest is wave-uniform base + lane*16.
__device__ __forceinline__ void gld_lds16(const void* g, void* l){
  __builtin_amdgcn_global_load_lds(
      (const __attribute__((address_space(1))) unsigned int*)g,
      (__attribute__((address_space(3))) unsigned int*)l, 16, 0, 0);
}

// Branch-free exact-GELU via Abramowitz-Stegun 7.1.26 erf (|err|<=1.5e-7).
// Verified R4: removed the 54%-VALUBusy erff dispatches.
__device__ __forceinline__ float fast_gelu(float v){
  const float x  = v * 0.70710678118654752f;
  const float ax = fabsf(x);
  const float t  = __builtin_amdgcn_rcpf(fmaf(0.3275911f, ax, 1.0f));
  float p = fmaf(t, 1.061405429f, -1.453152027f);
  p = fmaf(t, p, 1.421413741f);
  p = fmaf(t, p, -0.284496736f);
  p = fmaf(t, p, 0.254829592f);
  p = p * t;
  const float e = __expf(-ax * ax);
  const float erf_ax = fmaf(-p, e, 1.0f);
  const float erf_x  = copysignf(erf_ax, x);
  return 0.5f * v * (1.0f + erf_x);
}

// ---------------------------------------------------------------------------
// MFMA GEMM: C[M,N] = act(A @ W^T + bias) (+res / +dscale*res), bf16 in/out.
// 64x128 block tile, 4 waves (wave tile 32x64), BK=32, 2-deep LDS ring,
// counted vmcnt (R6/R7-verified). T2 source-side swizzle: ds_read conflict-
// free (verified 2.1M -> 0). XCD-chunked bijective blockIdx swizzle.
// R8: LDS-REPACK EPILOGUE — R7 counters showed the z-GEMM epilogue issuing
// 32 scalar 2B stores/thread (~128B useful/instr, heavy address VALU):
// VALUBusy 42%, 1.33 TB/s, dur 59us. After the K-loop the staging LDS is
// dead; stage the activated tile into a padded [64][136] bf16 LDS buffer,
// barrier, then 4 coalesced b128 stores/thread (1KB/wave-instr).
// FLAGS: 1=bias  2=+res(bf16)  4=+dscale[n]*res(bf16).  ACT: 1=GELU.
// ---------------------------------------------------------------------------
#define RPSTR 136   // repack row stride in shorts: 272B = 16B-aligned, breaks quad alias

template<int ACT, int FLAGS>
__global__ __launch_bounds__(256, 6) void mfma_gemm(
    int aSel, int lda, int wSel, int wOff, int ldw,
    int oSel, int ldc,
    const float* __restrict__ bias,
    int rSel, int ldres,
    const float* __restrict__ dscale,
    int K)
{
  const bf16* A = bufb(aSel);
  const bf16* W = bufb(wSel) + wOff;
  bf16* OB = bufb(oSel);
  const bf16* res = (rSel >= 0) ? bufb(rSel) : nullptr;

  // 24KB shared: staging As(8KB)+Ws(16KB) during K-loop; 64x136 bf16 (17.4KB)
  // repack buffer in the epilogue (staging is dead by then).
  __shared__ __align__(16) unsigned short lds[12288];
  unsigned short* As = lds;          // 2 x 2048 shorts
  unsigned short* Ws = lds + 4096;   // 2 x 4096 shorts

  // ---- XCD-chunked bijective blockIdx swizzle (m204 formula) ----
  const int gx = gridDim.x;
  const int nwg = gx * gridDim.y;
  const int orig = blockIdx.y * gx + blockIdx.x;
  const int q = nwg >> 3, r = nwg & 7;
  const int xcd = orig & 7, idx = orig >> 3;
  const int wg = (xcd < r ? xcd*(q+1) : r*(q+1) + (xcd-r)*q) + idx;
  const int bx = wg % gx, by = wg / gx;

  const int tid  = threadIdx.x;
  const int row0 = by * 64, col0 = bx * 128;
  const int lane = tid & 63;
  const int m16  = lane & 15, quad = lane >> 4;
  const int wv   = tid >> 6;
  const int wm   = (wv & 1) * 32, wn = (wv >> 1) * 64;

  // staging: wave w, lane l -> LDS row w*16 + (l>>2), slot (l&3).
  // Source k-group is XOR-swizzled by row ((r>>1)&3; consistent under r+=64).
  const int rlo = wv*16 + (lane >> 2);
  const int sg  = ((lane & 3) ^ ((rlo >> 1) & 3)) * 8;    // shorts
  const bf16* ga = &A[(size_t)(row0 + rlo)*lda + sg];
  const bf16* gw = &W[(size_t)(col0 + rlo)*ldw + sg];
  const size_t w64 = (size_t)64 * ldw;

  auto STAGE = [&](int bb, int k0){
    unsigned short* Ab = As + bb*2048;
    unsigned short* Wb = Ws + bb*4096;
    gld_lds16(ga + k0,       Ab + wv*512);
    gld_lds16(gw + k0,       Wb + wv*512);
    gld_lds16(gw + k0 + w64, Wb + 2048 + wv*512);
  };

  f32x4 acc[2][4] = {};
  const int nt = K >> 5;    // 8/16/32 for our shapes

  STAGE(0, 0); STAGE(1, 32);     // 6 vm loads/wave in flight

  for (int t = 0; t < nt; ++t){
    const int b = t & 1;
    // tile t resident when <= 3 younger loads outstanding
    if (t + 1 < nt) asm volatile("s_waitcnt vmcnt(3)" ::: "memory");
    else            asm volatile("s_waitcnt vmcnt(0)" ::: "memory");
    __builtin_amdgcn_s_barrier();            // all waves' portions resident

    const unsigned short* Ab = As + b*2048;
    const unsigned short* Wb = Ws + b*4096;
    bf16x8 af[2], wf[4];
    #pragma unroll
    for (int i = 0; i < 2; i++){
      const int rA = wm + 16*i + m16;
      af[i] = *reinterpret_cast<const bf16x8*>(&Ab[rA*32 + ((quad ^ ((rA>>1)&3))<<3)]);
    }
    #pragma unroll
    for (int j = 0; j < 4; j++){
      const int rW = wn + 16*j + m16;
      wf[j] = *reinterpret_cast<const bf16x8*>(&Wb[rW*32 + ((quad ^ ((rW>>1)&3))<<3)]);
    }
    asm volatile("s_waitcnt lgkmcnt(0)" ::: "memory");   // this wave's reads done
    __builtin_amdgcn_sched_barrier(0);                   // rule #18
    __builtin_amdgcn_s_barrier();                        // all waves done with buf b

    if (t + 2 < nt) STAGE(b, (t + 2) << 5);              // refill freed buffer

    __builtin_amdgcn_s_setprio(1);
    #pragma unroll
    for (int i = 0; i < 2; i++)
      #pragma unroll
      for (int j = 0; j < 4; j++)
        acc[i][j] = __builtin_amdgcn_mfma_f32_16x16x32_bf16(af[i], wf[j], acc[i][j], 0, 0, 0);
    __builtin_amdgcn_s_setprio(0);
  }
  // all staging ds_reads completed before the final barrier (lgkm0 enforced)
  // -> safe to overwrite lds with the repack tile now.

  // ---- epilogue phase 1: activate + write padded LDS tile ----
  // C/D layout col=lane&15, row=quad*4+reg (m89-verified)
  #pragma unroll
  for (int i = 0; i < 2; i++){
    #pragma unroll
    for (int j = 0; j < 4; j++){
      const int lcol = wn + 16*j + m16;
      const int col  = col0 + lcol;
      #pragma unroll
      for (int r2 = 0; r2 < 4; r2++){
        const int lrow = wm + 16*i + quad*4 + r2;
        const int row  = row0 + lrow;
        float v = acc[i][j][r2];
        if (FLAGS & 1) v += bias[col];
        if (ACT == 1)  v = fast_gelu(v);
        if (FLAGS & 2) v += __bfloat162float(res[(size_t)row*ldres + col]);
        if (FLAGS & 4) v += dscale[col] * __bfloat162float(res[(size_t)row*ldres + col]);
        bf16 bv = __float2bfloat16(v);
        lds[lrow*RPSTR + lcol] = *reinterpret_cast<unsigned short*>(&bv);
      }
    }
  }
  __syncthreads();

  // ---- epilogue phase 2: coalesced b128 stores (4 per thread) ----
  {
    const int orow = tid >> 2;          // 0..63
    const int oc   = (tid & 3) * 32;    // 0/32/64/96
    bf16* po = OB + (size_t)(row0 + orow)*ldc + col0 + oc;
    const unsigned short* ps = &lds[orow*RPSTR + oc];
    #pragma unroll
    for (int s = 0; s < 4; s++){
      uint4 d = *reinterpret_cast<const uint4*>(ps + s*8);
      *reinterpret_cast<uint4*>(po + s*8) = d;
    }
  }
}

// ---------------------------------------------------------------------------
// fp32 tiled GEMMs for the small ends (embed, out) — proven R12 structure.
// ---------------------------------------------------------------------------
__global__ __launch_bounds__(256) void emb_gemm(
    const float* __restrict__ x, const float* __restrict__ W,
    const float* __restrict__ b)
{
  __shared__ __align__(16) float Asx[16][68];
  __shared__ __align__(16) float Wsx[16][68];
  const int tid = threadIdx.x;
  const int tx = tid & 15, ty = tid >> 4;
  const int row0 = blockIdx.y * 64, col0 = blockIdx.x * 64;
  const int lc = tid & 15, lr = tid >> 4;
  float acc[4][4] = {};
  for (int k0 = 0; k0 < INDIM; k0 += 16){
    #pragma unroll
    for (int i = 0; i < 4; i++){
      Asx[lc][lr + 16*i] = x[(size_t)(row0 + lr + 16*i)*INDIM + k0 + lc];
      Wsx[lc][lr + 16*i] = W[(size_t)(col0 + lr + 16*i)*INDIM + k0 + lc];
    }
    __syncthreads();
    #pragma unroll
    for (int k = 0; k < 16; k++){
      float4 av = *reinterpret_cast<const float4*>(&Asx[k][ty*4]);
      float4 bv = *reinterpret_cast<const float4*>(&Wsx[k][tx*4]);
      float a[4] = {av.x, av.y, av.z, av.w};
      float b2[4] = {bv.x, bv.y, bv.z, bv.w};
      #pragma unroll
      for (int i = 0; i < 4; i++)
        #pragma unroll
        for (int j = 0; j < 4; j++)
          acc[i][j] = fmaf(a[i], b2[j], acc[i][j]);
    }
    __syncthreads();
  }
  #pragma unroll
  for (int i = 0; i < 4; i++){
    const int r = row0 + ty*4 + i;
    #pragma unroll
    for (int j = 0; j < 4; j++){
      const int cn = col0 + tx*4 + j;
      g_hb[(size_t)r*HIDD + cn] = __float2bfloat16(acc[i][j] + b[cn]);
    }
  }
}

__global__ __launch_bounds__(256) void out_gemm(
    const float* __restrict__ W, const float* __restrict__ b,
    float* __restrict__ out)
{
  __shared__ __align__(16) float Asx[16][68];
  __shared__ __align__(16) float Wsx[16][68];
  const int tid = threadIdx.x;
  const int tx = tid & 15, ty = tid >> 4;
  const int row0 = blockIdx.y * 64, col0 = blockIdx.x * 64;
  const int lc = tid & 15, lr = tid >> 4;
  float acc[4][4] = {};
  for (int k0 = 0; k0 < HIDD; k0 += 16){
    #pragma unroll
    for (int i = 0; i < 4; i++){
      Asx[lc][lr + 16*i] = __bfloat162float(g_hb[(size_t)(row0 + lr + 16*i)*HIDD + k0 + lc]);
      Wsx[lc][lr + 16*i] = W[(size_t)(col0 + lr + 16*i)*HIDD + k0 + lc];
    }
    __syncthreads();
    #pragma unroll
    for (int k = 0; k < 16; k++){
      float4 av = *reinterpret_cast<const float4*>(&Asx[k][ty*4]);
      float4 bv = *reinterpret_cast<const float4*>(&Wsx[k][tx*4]);
      float a[4] = {av.x, av.y, av.z, av.w};
      float b2[4] = {bv.x, bv.y, bv.z, bv.w};
      #pragma unroll
      for (int i = 0; i < 4; i++)
        #pragma unroll
        for (int j = 0; j < 4; j++)
          acc[i][j] = fmaf(a[i], b2[j], acc[i][j]);
    }
    __syncthreads();
  }
  #pragma unroll
  for (int i = 0; i < 4; i++){
    const int r = row0 + ty*4 + i;
    #pragma unroll
    for (int j = 0; j < 4; j++){
      const int cn = col0 + tx*4 + j;
      out[(size_t)r*OUTD + cn] = acc[i][j] + b[cn];
    }
  }
}

// ---------------------------------------------------------------------------
// lam_s = exp(-exp(nu)) * (cos(exp(th)) + i sin(exp(th)))
// ---------------------------------------------------------------------------
__device__ __forceinline__ void lam_of(const float* __restrict__ nu_log,
                                       const float* __restrict__ th_log,
                                       int s, float& lr, float& li)
{
  float nu  = expf(nu_log[s]);
  float th  = expf(th_log[s]);
  float mag = expf(-nu);
  lr = mag * cosf(th);
  li = mag * sinf(th);
}

// Carry-only local scan over 64-token chunks. Reads raw Bu (bf16), fp32 math.
__global__ __launch_bounds__(256) void scan_local(
    const float* __restrict__ nu_log, const float* __restrict__ th_log)
{
  const int blk = blockIdx.x;          // chunk 0..511
  const int s   = threadIdx.x;
  float lr, li; lam_of(nu_log, th_log, s, lr, li);
  float ar = 0.f, ai = 0.f;
  size_t base = (size_t)blk * CHUNK * 512 + s;
  for (int t = 0; t < CHUNK; t++){
    float br = __bfloat162float(g_bub[base + (size_t)t*512]);
    float bi = __bfloat162float(g_bub[base + (size_t)t*512 + 256]);
    float nr = fmaf(lr, ar, fmaf(-li, ai, br));
    float ni = fmaf(lr, ai, fmaf( li, ar, bi));
    ar = nr; ai = ni;
  }
  g_carry[(size_t)blk*512 + s]       = ar;
  g_carry[(size_t)blk*512 + 256 + s] = ai;
}

// Prefix accumulate + local re-scan seeded with prefix; overwrites g_bub
// in place with scan states (each element read once then written).
__global__ __launch_bounds__(256) void scan_fix(
    const float* __restrict__ nu_log, const float* __restrict__ th_log)
{
  const int blk = blockIdx.x;
  const int c   = blk & (NCHUNK - 1);
  const int s   = threadIdx.x;
  float lr, li; lam_of(nu_log, th_log, s, lr, li);
  float cr = 0.f, ci = 0.f;
  if (c > 0){
    float Tr = lr, Ti = li;
    #pragma unroll
    for (int i = 0; i < 6; i++){ float nr = Tr*Tr - Ti*Ti; Ti = 2.f*Tr*Ti; Tr = nr; }
    const int bstart = blk - c;
    for (int j = 0; j < c; j++){
      float er = g_carry[(size_t)(bstart + j)*512 + s];
      float ei = g_carry[(size_t)(bstart + j)*512 + 256 + s];
      float nr = fmaf(Tr, cr, fmaf(-Ti, ci, er));
      float ni = fmaf(Tr, ci, fmaf( Ti, cr, ei));
      cr = nr; ci = ni;
    }
  }
  // inclusive scan with incoming state (cr,ci)
  float ar = cr, ai = ci;
  size_t base = (size_t)blk * CHUNK * 512 + s;
  for (int t = 0; t < CHUNK; t++){
    size_t o = base + (size_t)t*512;
    float br = __bfloat162float(g_bub[o]);
    float bi = __bfloat162float(g_bub[o + 256]);
    float nr = fmaf(lr, ar, fmaf(-li, ai, br));
    float ni = fmaf(lr, ai, fmaf( li, ar, bi));
    ar = nr; ai = ni;
    g_bub[o]       = __float2bfloat16(ar);
    g_bub[o + 256] = __float2bfloat16(ai);
  }
}

// Pack B_norm for ALL layers -> bf16 (per layer 512 x 256)
__global__ __launch_bounds__(256) void pack_B(
    const float* __restrict__ Bre, const float* __restrict__ Bim,
    const float* __restrict__ gl)
{
  int idx = blockIdx.x * 256 + threadIdx.x;      // 0..NLAYERS*65536-1
  int l = idx >> 16, within = idx & 65535;
  int s = within >> 8;
  float g = expf(gl[l*STATE_D + s]);
  g_Bnb[(size_t)l*131072 + within]         = __float2bfloat16(Bre[idx] * g);
  g_Bnb[(size_t)l*131072 + 65536 + within] = __float2bfloat16(Bim[idx] * g);
}

// Pack Cw for ALL layers -> bf16 (per layer 256 x 512): [Cre | -Cim]
__global__ __launch_bounds__(256) void pack_C(
    const float* __restrict__ Cre, const float* __restrict__ Cim)
{
  int idx = blockIdx.x * 256 + threadIdx.x;      // 0..NLAYERS*65536-1
  int l = idx >> 16, within = idx & 65535;
  int h = within >> 8, s = within & 255;
  g_Cwb[(size_t)l*131072 + (size_t)h*512 + s]       = __float2bfloat16( Cre[idx]);
  g_Cwb[(size_t)l*131072 + (size_t)h*512 + 256 + s] = __float2bfloat16(-Cim[idx]);
}

// Straight fp32 -> bf16 weight convert into selected buffer
__global__ __launch_bounds__(256) void conv_bf16(
    const float* __restrict__ src, int dstSel, int n)
{
  int i = blockIdx.x * 256 + threadIdx.x;
  if (i < n) bufb(dstSel)[i] = __float2bfloat16(src[i]);
}

// ---------------------------------------------------------------------------
extern "C" void kernel_launch(void* const* d_in, const int* in_sizes, int n_in,
                              void* d_out, int out_size, void* d_ws, size_t ws_size,
                              hipStream_t stream)
{
  (void)d_ws; (void)ws_size; (void)out_size; (void)n_in; (void)in_sizes;
  const float* x      = (const float*)d_in[0];
  const float* emb_W  = (const float*)d_in[1];
  const float* emb_b  = (const float*)d_in[2];
  const float* nu_log = (const float*)d_in[3];
  const float* th_log = (const float*)d_in[4];
  const float* ga_log = (const float*)d_in[5];
  const float* B_re   = (const float*)d_in[6];
  const float* B_im   = (const float*)d_in[7];
  const float* C_re   = (const float*)d_in[8];
  const float* C_im   = (const float*)d_in[9];
  const float* Dv     = (const float*)d_in[10];
  const float* Wh     = (const float*)d_in[11];
  const float* bh     = (const float*)d_in[12];
  const float* Wo     = (const float*)d_in[13];
  const float* bo     = (const float*)d_in[14];
  const float* out_W  = (const float*)d_in[15];
  const float* out_b  = (const float*)d_in[16];

  const dim3 blk(256);

  // ---- all weight packing upfront (independent of activations) ----
  pack_B<<<dim3(NLAYERS*256), blk, 0, stream>>>(B_re, B_im, ga_log);
  pack_C<<<dim3(NLAYERS*256), blk, 0, stream>>>(C_re, C_im);
  conv_bf16<<<dim3(NLAYERS*1024), blk, 0, stream>>>(Wh, SB_WHB, NLAYERS*262144);
  conv_bf16<<<dim3(NLAYERS*1024), blk, 0, stream>>>(Wo, SB_WOB, NLAYERS*262144);

  // embed: h = x @ emb_W^T + emb_b  -> g_hb (bf16 only)
  emb_gemm<<<dim3(HIDD/64, M_TOK/64), blk, 0, stream>>>(x, emb_W, emb_b);

  for (int l = 0; l < NLAYERS; l++){
    // Bu = h @ Bn^T   (32768 x 512 x 256) -> g_bub bf16   [2048 blocks]
    mfma_gemm<0, 0><<<dim3(4, M_TOK/64), blk, 0, stream>>>(
        SB_HB, HIDD, SB_BNB, l*131072, HIDD, SB_BUB, 512,
        nullptr, -1, 0, nullptr, HIDD);

    // chunked scan (fp32 in registers, bf16 in memory, in-place states)
    scan_local<<<dim3(M_TOK/CHUNK), blk, 0, stream>>>(nu_log + l*STATE_D, th_log + l*STATE_D);
    scan_fix  <<<dim3(M_TOK/CHUNK), blk, 0, stream>>>(nu_log + l*STATE_D, th_log + l*STATE_D);

    // y = states @ Cw^T + D*h   (32768 x 256 x 512) -> g_yb  [1024 blocks]
    mfma_gemm<0, 4><<<dim3(2, M_TOK/64), blk, 0, stream>>>(
        SB_BUB, 512, SB_CWB, l*131072, 512, SB_YB, HIDD,
        nullptr, SB_HB, HIDD, Dv + l*HIDD, 512);

    // z = gelu(y @ Wh^T + bh)   (32768 x 1024 x 256) -> g_zb  [4096 blocks]
    mfma_gemm<1, 1><<<dim3(8, M_TOK/64), blk, 0, stream>>>(
        SB_YB, HIDD, SB_WHB, l*262144, STATE_D, SB_ZB, MLPD,
        bh + l*MLPD, -1, 0, nullptr, STATE_D);

    // h = z @ Wo^T + bo + y     (32768 x 256 x 1024) -> g_hb  [1024 blocks]
    mfma_gemm<0, 3><<<dim3(2, M_TOK/64), blk, 0, stream>>>(
        SB_ZB, MLPD, SB_WOB, l*262144, MLPD, SB_HB, HIDD,
        bo + l*HIDD, SB_YB, HIDD, nullptr, MLPD);
  }

  // out = h @ out_W^T + out_b  (fp32 GEMM reading bf16 A, fp32 store)
  out_gemm<<<dim3(OUTD/64, M_TOK/64), blk, 0, stream>>>(out_W, out_b, (float*)d_out);
}

// Round 9
// 836.855 us; speedup vs baseline: 1.5278x; 1.0219x over previous
//
#include <hip/hip_runtime.h>
#include <hip/hip_bf16.h>
#include <math.h>

typedef __hip_bfloat16 bf16;
typedef __attribute__((ext_vector_type(8))) short bf16x8;   // 8 bf16 = 4 VGPR
typedef __attribute__((ext_vector_type(4))) float f32x4;    // MFMA acc

#define BATCH   16
#define SEQLEN  2048
#define INDIM   64
#define HIDD    256
#define STATE_D 256
#define MLPD    1024
#define OUTD    128
#define NLAYERS 4
#define M_TOK   (BATCH*SEQLEN)     // 32768 tokens
#define CHUNK   64
#define NCHUNK  (SEQLEN/CHUNK)     // 32 chunks per batch

// ---- ALL-BF16 activation chain (R7-verified: fp32 masters were the dominant
// byte stream; storage rounding second-order vs bf16-MFMA error) ------------
__device__ float g_carry[512*512];          // fp32 scan carries (tiny)
__device__ bf16  g_hb [(size_t)M_TOK*256];
__device__ bf16  g_yb [(size_t)M_TOK*256];
__device__ bf16  g_bub[(size_t)M_TOK*512];  // raw Bu, then scan states (in place)
__device__ bf16  g_zb [(size_t)M_TOK*1024];
// per-layer packed weights (hoisted out of the layer loop)
__device__ bf16  g_Bnb[NLAYERS*512*256];    // B_norm: rows 0-255 re, 256-511 im
__device__ bf16  g_Cwb[NLAYERS*256*512];    // [Cre | -Cim]
__device__ bf16  g_Whb[NLAYERS*1024*256];
__device__ bf16  g_Wob[NLAYERS*256*1024];

#define SB_HB  0
#define SB_YB  1
#define SB_BUB 2
#define SB_ZB  3
#define SB_BNB 4
#define SB_CWB 5
#define SB_WHB 6
#define SB_WOB 7

__device__ __forceinline__ bf16* bufb(int sel){
  switch(sel){
    case SB_HB:  return g_hb;  case SB_YB:  return g_yb;
    case SB_BUB: return g_bub; case SB_ZB:  return g_zb;
    case SB_BNB: return g_Bnb; case SB_CWB: return g_Cwb;
    case SB_WHB: return g_Whb; default:     return g_Wob; }
}

// async global->LDS, 16B per lane. LDS dest is wave-uniform base + lane*16.
__device__ __forceinline__ void gld_lds16(const void* g, void* l){
  __builtin_amdgcn_global_load_lds(
      (const __attribute__((address_space(1))) unsigned int*)g,
      (__attribute__((address_space(3))) unsigned int*)l, 16, 0, 0);
}

// Branch-free exact-GELU via Abramowitz-Stegun 7.1.26 erf (|err|<=1.5e-7).
// Verified R4: removed the 54%-VALUBusy erff dispatches.
__device__ __forceinline__ float fast_gelu(float v){
  const float x  = v * 0.70710678118654752f;
  const float ax = fabsf(x);
  const float t  = __builtin_amdgcn_rcpf(fmaf(0.3275911f, ax, 1.0f));
  float p = fmaf(t, 1.061405429f, -1.453152027f);
  p = fmaf(t, p, 1.421413741f);
  p = fmaf(t, p, -0.284496736f);
  p = fmaf(t, p, 0.254829592f);
  p = p * t;
  const float e = __expf(-ax * ax);
  const float erf_ax = fmaf(-p, e, 1.0f);
  const float erf_x  = copysignf(erf_ax, x);
  return 0.5f * v * (1.0f + erf_x);
}

// ---------------------------------------------------------------------------
// MFMA GEMM: C[M,N] = act(A @ W^T + bias) (+res / +dscale*res), bf16 in/out.
// 64x128 block tile, 4 waves (wave tile 32x64), BK=32, 2-deep LDS ring,
// counted vmcnt (R6/R7-verified). T2 source-side swizzle: ds_read conflict-
// free (verified 2.1M -> 0). XCD-chunked bijective blockIdx swizzle.
// LDS-repack epilogue (R8) with DENSE store mapping (R9 fix): R8's mapping
// gave each thread a 64B-contiguous run -> each store instruction touched 16
// rows with one 16B piece per 64B span (partial lines; z-GEMM write BW fell
// 1.33->1.13 TB/s). Now each store instruction writes 4 COMPLETE 256B row
// segments (wave = 4 rows x 16 lanes x 16B), 4 instructions per thread.
// FLAGS: 1=bias  2=+res(bf16)  4=+dscale[n]*res(bf16).  ACT: 1=GELU.
// ---------------------------------------------------------------------------
#define RPSTR 136   // repack row stride in shorts: 272B = 16B-aligned, breaks quad alias

template<int ACT, int FLAGS>
__global__ __launch_bounds__(256, 6) void mfma_gemm(
    int aSel, int lda, int wSel, int wOff, int ldw,
    int oSel, int ldc,
    const float* __restrict__ bias,
    int rSel, int ldres,
    const float* __restrict__ dscale,
    int K)
{
  const bf16* A = bufb(aSel);
  const bf16* W = bufb(wSel) + wOff;
  bf16* OB = bufb(oSel);
  const bf16* res = (rSel >= 0) ? bufb(rSel) : nullptr;

  // 24KB shared: staging As(8KB)+Ws(16KB) during K-loop; 64x136 bf16 (17.4KB)
  // repack buffer in the epilogue (staging is dead by then).
  __shared__ __align__(16) unsigned short lds[12288];
  unsigned short* As = lds;          // 2 x 2048 shorts
  unsigned short* Ws = lds + 4096;   // 2 x 4096 shorts

  // ---- XCD-chunked bijective blockIdx swizzle (m204 formula) ----
  const int gx = gridDim.x;
  const int nwg = gx * gridDim.y;
  const int orig = blockIdx.y * gx + blockIdx.x;
  const int q = nwg >> 3, r = nwg & 7;
  const int xcd = orig & 7, idx = orig >> 3;
  const int wg = (xcd < r ? xcd*(q+1) : r*(q+1) + (xcd-r)*q) + idx;
  const int bx = wg % gx, by = wg / gx;

  const int tid  = threadIdx.x;
  const int row0 = by * 64, col0 = bx * 128;
  const int lane = tid & 63;
  const int m16  = lane & 15, quad = lane >> 4;
  const int wv   = tid >> 6;
  const int wm   = (wv & 1) * 32, wn = (wv >> 1) * 64;

  // staging: wave w, lane l -> LDS row w*16 + (l>>2), slot (l&3).
  // Source k-group is XOR-swizzled by row ((r>>1)&3; consistent under r+=64).
  const int rlo = wv*16 + (lane >> 2);
  const int sg  = ((lane & 3) ^ ((rlo >> 1) & 3)) * 8;    // shorts
  const bf16* ga = &A[(size_t)(row0 + rlo)*lda + sg];
  const bf16* gw = &W[(size_t)(col0 + rlo)*ldw + sg];
  const size_t w64 = (size_t)64 * ldw;

  auto STAGE = [&](int bb, int k0){
    unsigned short* Ab = As + bb*2048;
    unsigned short* Wb = Ws + bb*4096;
    gld_lds16(ga + k0,       Ab + wv*512);
    gld_lds16(gw + k0,       Wb + wv*512);
    gld_lds16(gw + k0 + w64, Wb + 2048 + wv*512);
  };

  f32x4 acc[2][4] = {};
  const int nt = K >> 5;    // 8/16/32 for our shapes

  STAGE(0, 0); STAGE(1, 32);     // 6 vm loads/wave in flight

  for (int t = 0; t < nt; ++t){
    const int b = t & 1;
    // tile t resident when <= 3 younger loads outstanding
    if (t + 1 < nt) asm volatile("s_waitcnt vmcnt(3)" ::: "memory");
    else            asm volatile("s_waitcnt vmcnt(0)" ::: "memory");
    __builtin_amdgcn_s_barrier();            // all waves' portions resident

    const unsigned short* Ab = As + b*2048;
    const unsigned short* Wb = Ws + b*4096;
    bf16x8 af[2], wf[4];
    #pragma unroll
    for (int i = 0; i < 2; i++){
      const int rA = wm + 16*i + m16;
      af[i] = *reinterpret_cast<const bf16x8*>(&Ab[rA*32 + ((quad ^ ((rA>>1)&3))<<3)]);
    }
    #pragma unroll
    for (int j = 0; j < 4; j++){
      const int rW = wn + 16*j + m16;
      wf[j] = *reinterpret_cast<const bf16x8*>(&Wb[rW*32 + ((quad ^ ((rW>>1)&3))<<3)]);
    }
    asm volatile("s_waitcnt lgkmcnt(0)" ::: "memory");   // this wave's reads done
    __builtin_amdgcn_sched_barrier(0);                   // rule #18
    __builtin_amdgcn_s_barrier();                        // all waves done with buf b

    if (t + 2 < nt) STAGE(b, (t + 2) << 5);              // refill freed buffer

    __builtin_amdgcn_s_setprio(1);
    #pragma unroll
    for (int i = 0; i < 2; i++)
      #pragma unroll
      for (int j = 0; j < 4; j++)
        acc[i][j] = __builtin_amdgcn_mfma_f32_16x16x32_bf16(af[i], wf[j], acc[i][j], 0, 0, 0);
    __builtin_amdgcn_s_setprio(0);
  }
  // all staging ds_reads completed before the final barrier (lgkm0 enforced)
  // -> safe to overwrite lds with the repack tile now.

  // ---- epilogue phase 1: activate + write padded LDS tile ----
  // C/D layout col=lane&15, row=quad*4+reg (m89-verified)
  #pragma unroll
  for (int i = 0; i < 2; i++){
    #pragma unroll
    for (int j = 0; j < 4; j++){
      const int lcol = wn + 16*j + m16;
      const int col  = col0 + lcol;
      #pragma unroll
      for (int r2 = 0; r2 < 4; r2++){
        const int lrow = wm + 16*i + quad*4 + r2;
        const int row  = row0 + lrow;
        float v = acc[i][j][r2];
        if (FLAGS & 1) v += bias[col];
        if (ACT == 1)  v = fast_gelu(v);
        if (FLAGS & 2) v += __bfloat162float(res[(size_t)row*ldres + col]);
        if (FLAGS & 4) v += dscale[col] * __bfloat162float(res[(size_t)row*ldres + col]);
        bf16 bv = __float2bfloat16(v);
        lds[lrow*RPSTR + lcol] = *reinterpret_cast<unsigned short*>(&bv);
      }
    }
  }
  __syncthreads();

  // ---- epilogue phase 2: DENSE coalesced b128 stores ----
  // Per store instruction: wave covers 4 complete rows (16 lanes x 16B =
  // 256B contiguous per row). 4 instructions cover the 64x128 tile.
  {
    const int rr  = tid >> 4;           // 0..15 (row within 16-row group)
    const int c16 = (tid & 15) * 8;     // col in shorts (0..120)
    #pragma unroll
    for (int s = 0; s < 4; s++){
      const int orow = s*16 + rr;
      uint4 d = *reinterpret_cast<const uint4*>(&lds[orow*RPSTR + c16]);
      *reinterpret_cast<uint4*>(OB + (size_t)(row0 + orow)*ldc + col0 + c16) = d;
    }
  }
}

// ---------------------------------------------------------------------------
// fp32 tiled GEMMs for the small ends (embed, out) — proven R12 structure.
// ---------------------------------------------------------------------------
__global__ __launch_bounds__(256) void emb_gemm(
    const float* __restrict__ x, const float* __restrict__ W,
    const float* __restrict__ b)
{
  __shared__ __align__(16) float Asx[16][68];
  __shared__ __align__(16) float Wsx[16][68];
  const int tid = threadIdx.x;
  const int tx = tid & 15, ty = tid >> 4;
  const int row0 = blockIdx.y * 64, col0 = blockIdx.x * 64;
  const int lc = tid & 15, lr = tid >> 4;
  float acc[4][4] = {};
  for (int k0 = 0; k0 < INDIM; k0 += 16){
    #pragma unroll
    for (int i = 0; i < 4; i++){
      Asx[lc][lr + 16*i] = x[(size_t)(row0 + lr + 16*i)*INDIM + k0 + lc];
      Wsx[lc][lr + 16*i] = W[(size_t)(col0 + lr + 16*i)*INDIM + k0 + lc];
    }
    __syncthreads();
    #pragma unroll
    for (int k = 0; k < 16; k++){
      float4 av = *reinterpret_cast<const float4*>(&Asx[k][ty*4]);
      float4 bv = *reinterpret_cast<const float4*>(&Wsx[k][tx*4]);
      float a[4] = {av.x, av.y, av.z, av.w};
      float b2[4] = {bv.x, bv.y, bv.z, bv.w};
      #pragma unroll
      for (int i = 0; i < 4; i++)
        #pragma unroll
        for (int j = 0; j < 4; j++)
          acc[i][j] = fmaf(a[i], b2[j], acc[i][j]);
    }
    __syncthreads();
  }
  #pragma unroll
  for (int i = 0; i < 4; i++){
    const int r = row0 + ty*4 + i;
    #pragma unroll
    for (int j = 0; j < 4; j++){
      const int cn = col0 + tx*4 + j;
      g_hb[(size_t)r*HIDD + cn] = __float2bfloat16(acc[i][j] + b[cn]);
    }
  }
}

__global__ __launch_bounds__(256) void out_gemm(
    const float* __restrict__ W, const float* __restrict__ b,
    float* __restrict__ out)
{
  __shared__ __align__(16) float Asx[16][68];
  __shared__ __align__(16) float Wsx[16][68];
  const int tid = threadIdx.x;
  const int tx = tid & 15, ty = tid >> 4;
  const int row0 = blockIdx.y * 64, col0 = blockIdx.x * 64;
  const int lc = tid & 15, lr = tid >> 4;
  float acc[4][4] = {};
  for (int k0 = 0; k0 < HIDD; k0 += 16){
    #pragma unroll
    for (int i = 0; i < 4; i++){
      Asx[lc][lr + 16*i] = __bfloat162float(g_hb[(size_t)(row0 + lr + 16*i)*HIDD + k0 + lc]);
      Wsx[lc][lr + 16*i] = W[(size_t)(col0 + lr + 16*i)*HIDD + k0 + lc];
    }
    __syncthreads();
    #pragma unroll
    for (int k = 0; k < 16; k++){
      float4 av = *reinterpret_cast<const float4*>(&Asx[k][ty*4]);
      float4 bv = *reinterpret_cast<const float4*>(&Wsx[k][tx*4]);
      float a[4] = {av.x, av.y, av.z, av.w};
      float b2[4] = {bv.x, bv.y, bv.z, bv.w};
      #pragma unroll
      for (int i = 0; i < 4; i++)
        #pragma unroll
        for (int j = 0; j < 4; j++)
          acc[i][j] = fmaf(a[i], b2[j], acc[i][j]);
    }
    __syncthreads();
  }
  #pragma unroll
  for (int i = 0; i < 4; i++){
    const int r = row0 + ty*4 + i;
    #pragma unroll
    for (int j = 0; j < 4; j++){
      const int cn = col0 + tx*4 + j;
      out[(size_t)r*OUTD + cn] = acc[i][j] + b[cn];
    }
  }
}

// ---------------------------------------------------------------------------
// lam_s = exp(-exp(nu)) * (cos(exp(th)) + i sin(exp(th)))
// ---------------------------------------------------------------------------
__device__ __forceinline__ void lam_of(const float* __restrict__ nu_log,
                                       const float* __restrict__ th_log,
                                       int s, float& lr, float& li)
{
  float nu  = expf(nu_log[s]);
  float th  = expf(th_log[s]);
  float mag = expf(-nu);
  lr = mag * cosf(th);
  li = mag * sinf(th);
}

// Carry-only local scan over 64-token chunks. Reads raw Bu (bf16), fp32 math.
__global__ __launch_bounds__(256) void scan_local(
    const float* __restrict__ nu_log, const float* __restrict__ th_log)
{
  const int blk = blockIdx.x;          // chunk 0..511
  const int s   = threadIdx.x;
  float lr, li; lam_of(nu_log, th_log, s, lr, li);
  float ar = 0.f, ai = 0.f;
  size_t base = (size_t)blk * CHUNK * 512 + s;
  for (int t = 0; t < CHUNK; t++){
    float br = __bfloat162float(g_bub[base + (size_t)t*512]);
    float bi = __bfloat162float(g_bub[base + (size_t)t*512 + 256]);
    float nr = fmaf(lr, ar, fmaf(-li, ai, br));
    float ni = fmaf(lr, ai, fmaf( li, ar, bi));
    ar = nr; ai = ni;
  }
  g_carry[(size_t)blk*512 + s]       = ar;
  g_carry[(size_t)blk*512 + 256 + s] = ai;
}

// Prefix accumulate + local re-scan seeded with prefix; overwrites g_bub
// in place with scan states (each element read once then written).
__global__ __launch_bounds__(256) void scan_fix(
    const float* __restrict__ nu_log, const float* __restrict__ th_log)
{
  const int blk = blockIdx.x;
  const int c   = blk & (NCHUNK - 1);
  const int s   = threadIdx.x;
  float lr, li; lam_of(nu_log, th_log, s, lr, li);
  float cr = 0.f, ci = 0.f;
  if (c > 0){
    float Tr = lr, Ti = li;
    #pragma unroll
    for (int i = 0; i < 6; i++){ float nr = Tr*Tr - Ti*Ti; Ti = 2.f*Tr*Ti; Tr = nr; }
    const int bstart = blk - c;
    for (int j = 0; j < c; j++){
      float er = g_carry[(size_t)(bstart + j)*512 + s];
      float ei = g_carry[(size_t)(bstart + j)*512 + 256 + s];
      float nr = fmaf(Tr, cr, fmaf(-Ti, ci, er));
      float ni = fmaf(Tr, ci, fmaf( Ti, cr, ei));
      cr = nr; ci = ni;
    }
  }
  // inclusive scan with incoming state (cr,ci)
  float ar = cr, ai = ci;
  size_t base = (size_t)blk * CHUNK * 512 + s;
  for (int t = 0; t < CHUNK; t++){
    size_t o = base + (size_t)t*512;
    float br = __bfloat162float(g_bub[o]);
    float bi = __bfloat162float(g_bub[o + 256]);
    float nr = fmaf(lr, ar, fmaf(-li, ai, br));
    float ni = fmaf(lr, ai, fmaf( li, ar, bi));
    ar = nr; ai = ni;
    g_bub[o]       = __float2bfloat16(ar);
    g_bub[o + 256] = __float2bfloat16(ai);
  }
}

// Pack B_norm for ALL layers -> bf16 (per layer 512 x 256)
__global__ __launch_bounds__(256) void pack_B(
    const float* __restrict__ Bre, const float* __restrict__ Bim,
    const float* __restrict__ gl)
{
  int idx = blockIdx.x * 256 + threadIdx.x;      // 0..NLAYERS*65536-1
  int l = idx >> 16, within = idx & 65535;
  int s = within >> 8;
  float g = expf(gl[l*STATE_D + s]);
  g_Bnb[(size_t)l*131072 + within]         = __float2bfloat16(Bre[idx] * g);
  g_Bnb[(size_t)l*131072 + 65536 + within] = __float2bfloat16(Bim[idx] * g);
}

// Pack Cw for ALL layers -> bf16 (per layer 256 x 512): [Cre | -Cim]
__global__ __launch_bounds__(256) void pack_C(
    const float* __restrict__ Cre, const float* __restrict__ Cim)
{
  int idx = blockIdx.x * 256 + threadIdx.x;      // 0..NLAYERS*65536-1
  int l = idx >> 16, within = idx & 65535;
  int h = within >> 8, s = within & 255;
  g_Cwb[(size_t)l*131072 + (size_t)h*512 + s]       = __float2bfloat16( Cre[idx]);
  g_Cwb[(size_t)l*131072 + (size_t)h*512 + 256 + s] = __float2bfloat16(-Cim[idx]);
}

// Straight fp32 -> bf16 weight convert into selected buffer
__global__ __launch_bounds__(256) void conv_bf16(
    const float* __restrict__ src, int dstSel, int n)
{
  int i = blockIdx.x * 256 + threadIdx.x;
  if (i < n) bufb(dstSel)[i] = __float2bfloat16(src[i]);
}

// ---------------------------------------------------------------------------
extern "C" void kernel_launch(void* const* d_in, const int* in_sizes, int n_in,
                              void* d_out, int out_size, void* d_ws, size_t ws_size,
                              hipStream_t stream)
{
  (void)d_ws; (void)ws_size; (void)out_size; (void)n_in; (void)in_sizes;
  const float* x      = (const float*)d_in[0];
  const float* emb_W  = (const float*)d_in[1];
  const float* emb_b  = (const float*)d_in[2];
  const float* nu_log = (const float*)d_in[3];
  const float* th_log = (const float*)d_in[4];
  const float* ga_log = (const float*)d_in[5];
  const float* B_re   = (const float*)d_in[6];
  const float* B_im   = (const float*)d_in[7];
  const float* C_re   = (const float*)d_in[8];
  const float* C_im   = (const float*)d_in[9];
  const float* Dv     = (const float*)d_in[10];
  const float* Wh     = (const float*)d_in[11];
  const float* bh     = (const float*)d_in[12];
  const float* Wo     = (const float*)d_in[13];
  const float* bo     = (const float*)d_in[14];
  const float* out_W  = (const float*)d_in[15];
  const float* out_b  = (const float*)d_in[16];

  const dim3 blk(256);

  // ---- all weight packing upfront (independent of activations) ----
  pack_B<<<dim3(NLAYERS*256), blk, 0, stream>>>(B_re, B_im, ga_log);
  pack_C<<<dim3(NLAYERS*256), blk, 0, stream>>>(C_re, C_im);
  conv_bf16<<<dim3(NLAYERS*1024), blk, 0, stream>>>(Wh, SB_WHB, NLAYERS*262144);
  conv_bf16<<<dim3(NLAYERS*1024), blk, 0, stream>>>(Wo, SB_WOB, NLAYERS*262144);

  // embed: h = x @ emb_W^T + emb_b  -> g_hb (bf16 only)
  emb_gemm<<<dim3(HIDD/64, M_TOK/64), blk, 0, stream>>>(x, emb_W, emb_b);

  for (int l = 0; l < NLAYERS; l++){
    // Bu = h @ Bn^T   (32768 x 512 x 256) -> g_bub bf16   [2048 blocks]
    mfma_gemm<0, 0><<<dim3(4, M_TOK/64), blk, 0, stream>>>(
        SB_HB, HIDD, SB_BNB, l*131072, HIDD, SB_BUB, 512,
        nullptr, -1, 0, nullptr, HIDD);

    // chunked scan (fp32 in registers, bf16 in memory, in-place states)
    scan_local<<<dim3(M_TOK/CHUNK), blk, 0, stream>>>(nu_log + l*STATE_D, th_log + l*STATE_D);
    scan_fix  <<<dim3(M_TOK/CHUNK), blk, 0, stream>>>(nu_log + l*STATE_D, th_log + l*STATE_D);

    // y = states @ Cw^T + D*h   (32768 x 256 x 512) -> g_yb  [1024 blocks]
    mfma_gemm<0, 4><<<dim3(2, M_TOK/64), blk, 0, stream>>>(
        SB_BUB, 512, SB_CWB, l*131072, 512, SB_YB, HIDD,
        nullptr, SB_HB, HIDD, Dv + l*HIDD, 512);

    // z = gelu(y @ Wh^T + bh)   (32768 x 1024 x 256) -> g_zb  [4096 blocks]
    mfma_gemm<1, 1><<<dim3(8, M_TOK/64), blk, 0, stream>>>(
        SB_YB, HIDD, SB_WHB, l*262144, STATE_D, SB_ZB, MLPD,
        bh + l*MLPD, -1, 0, nullptr, STATE_D);

    // h = z @ Wo^T + bo + y     (32768 x 256 x 1024) -> g_hb  [1024 blocks]
    mfma_gemm<0, 3><<<dim3(2, M_TOK/64), blk, 0, stream>>>(
        SB_ZB, MLPD, SB_WOB, l*262144, MLPD, SB_HB, HIDD,
        bo + l*HIDD, SB_YB, HIDD, nullptr, MLPD);
  }

  // out = h @ out_W^T + out_b  (fp32 GEMM reading bf16 A, fp32 store)
  out_gemm<<<dim3(OUTD/64, M_TOK/64), blk, 0, stream>>>(out_W, out_b, (float*)d_out);
}

// Round 10
// 809.859 us; speedup vs baseline: 1.5788x; 1.0333x over previous
//
#include <hip/hip_runtime.h>
#include <hip/hip_bf16.h>
#include <math.h>

typedef __hip_bfloat16 bf16;
typedef __attribute__((ext_vector_type(8))) short bf16x8;   // 8 bf16 = 4 VGPR
typedef __attribute__((ext_vector_type(4))) float f32x4;    // MFMA acc

#define BATCH   16
#define SEQLEN  2048
#define INDIM   64
#define HIDD    256
#define STATE_D 256
#define MLPD    1024
#define OUTD    128
#define NLAYERS 4
#define M_TOK   (BATCH*SEQLEN)     // 32768 tokens
#define CHUNK   64
#define NCHUNK  (SEQLEN/CHUNK)     // 32 chunks per batch

// ---- ALL-BF16 activation chain (R7-verified). COMPLEX-INTERLEAVED state
// layout (R10): Bu/state col 2s = re_s, col 2s+1 = im_s. Lets each Bu block
// (64 tokens x 128 cols = 64 COMPLETE complex states) compute its chunk
// carry in the epilogue from the repack LDS — scan_local deleted. ----------
__device__ float g_carry[512*512];          // fp32 carries [chunk][2s|2s+1]
__device__ bf16  g_hb [(size_t)M_TOK*256];
__device__ bf16  g_yb [(size_t)M_TOK*256];
__device__ bf16  g_bub[(size_t)M_TOK*512];  // raw Bu, then scan states (in place)
__device__ bf16  g_zb [(size_t)M_TOK*1024];
// per-layer packed weights (hoisted out of the layer loop)
__device__ bf16  g_Bnb[NLAYERS*512*256];    // B_norm rows interleaved: 2s=re, 2s+1=im
__device__ bf16  g_Cwb[NLAYERS*256*512];    // cols interleaved: 2s=Cre, 2s+1=-Cim
__device__ bf16  g_Whb[NLAYERS*1024*256];
__device__ bf16  g_Wob[NLAYERS*256*1024];

#define SB_HB  0
#define SB_YB  1
#define SB_BUB 2
#define SB_ZB  3
#define SB_BNB 4
#define SB_CWB 5
#define SB_WHB 6
#define SB_WOB 7

__device__ __forceinline__ bf16* bufb(int sel){
  switch(sel){
    case SB_HB:  return g_hb;  case SB_YB:  return g_yb;
    case SB_BUB: return g_bub; case SB_ZB:  return g_zb;
    case SB_BNB: return g_Bnb; case SB_CWB: return g_Cwb;
    case SB_WHB: return g_Whb; default:     return g_Wob; }
}

// async global->LDS, 16B per lane. LDS dest is wave-uniform base + lane*16.
__device__ __forceinline__ void gld_lds16(const void* g, void* l){
  __builtin_amdgcn_global_load_lds(
      (const __attribute__((address_space(1))) unsigned int*)g,
      (__attribute__((address_space(3))) unsigned int*)l, 16, 0, 0);
}

// Branch-free exact-GELU via Abramowitz-Stegun 7.1.26 erf (|err|<=1.5e-7).
__device__ __forceinline__ float fast_gelu(float v){
  const float x  = v * 0.70710678118654752f;
  const float ax = fabsf(x);
  const float t  = __builtin_amdgcn_rcpf(fmaf(0.3275911f, ax, 1.0f));
  float p = fmaf(t, 1.061405429f, -1.453152027f);
  p = fmaf(t, p, 1.421413741f);
  p = fmaf(t, p, -0.284496736f);
  p = fmaf(t, p, 0.254829592f);
  p = p * t;
  const float e = __expf(-ax * ax);
  const float erf_ax = fmaf(-p, e, 1.0f);
  const float erf_x  = copysignf(erf_ax, x);
  return 0.5f * v * (1.0f + erf_x);
}

// lam_s = exp(-exp(nu)) * (cos(exp(th)) + i sin(exp(th)))
__device__ __forceinline__ void lam_of(const float* __restrict__ nu_log,
                                       const float* __restrict__ th_log,
                                       int s, float& lr, float& li)
{
  float nu  = expf(nu_log[s]);
  float th  = expf(th_log[s]);
  float mag = expf(-nu);
  lr = mag * cosf(th);
  li = mag * sinf(th);
}

// ---------------------------------------------------------------------------
// MFMA GEMM: C[M,N] = act(A @ W^T + bias) (+res / +dscale*res), bf16 in/out.
// 64x128 block tile, 4 waves (wave tile 32x64), BK=32, 2-deep LDS ring,
// counted vmcnt (R6/R7-verified). T2 source-side swizzle (conflicts 2.1M->0).
// XCD-chunked bijective blockIdx swizzle. LDS-repack epilogue with DENSE
// b128 stores (R9: z 69->52us, write BW restored).
// FLAGS: 1=bias  2=+res  4=+dscale[n]*res  8=CHUNK-CARRY (Bu only): after
// the repack, 64 lanes run the 64-token local scan over the LDS tile (each
// block = exactly one chunk x 64 complex states, interleaved layout) and
// write g_carry — replaces the scan_local kernel (32 MB re-read x4 layers).
// ---------------------------------------------------------------------------
#define RPSTR 136   // repack row stride in shorts

template<int ACT, int FLAGS>
__global__ __launch_bounds__(256, 6) void mfma_gemm(
    int aSel, int lda, int wSel, int wOff, int ldw,
    int oSel, int ldc,
    const float* __restrict__ bias,
    int rSel, int ldres,
    const float* __restrict__ dscale,
    int K,
    const float* __restrict__ nu_log,
    const float* __restrict__ th_log)
{
  const bf16* A = bufb(aSel);
  const bf16* W = bufb(wSel) + wOff;
  bf16* OB = bufb(oSel);
  const bf16* res = (rSel >= 0) ? bufb(rSel) : nullptr;

  // 24KB shared: staging As(8KB)+Ws(16KB) during K-loop; 64x136 bf16 repack
  // buffer in the epilogue (staging dead by then).
  __shared__ __align__(16) unsigned short lds[12288];
  unsigned short* As = lds;          // 2 x 2048 shorts
  unsigned short* Ws = lds + 4096;   // 2 x 4096 shorts

  // ---- XCD-chunked bijective blockIdx swizzle (m204 formula) ----
  const int gx = gridDim.x;
  const int nwg = gx * gridDim.y;
  const int orig = blockIdx.y * gx + blockIdx.x;
  const int q = nwg >> 3, r = nwg & 7;
  const int xcd = orig & 7, idx = orig >> 3;
  const int wg = (xcd < r ? xcd*(q+1) : r*(q+1) + (xcd-r)*q) + idx;
  const int bx = wg % gx, by = wg / gx;

  const int tid  = threadIdx.x;
  const int row0 = by * 64, col0 = bx * 128;
  const int lane = tid & 63;
  const int m16  = lane & 15, quad = lane >> 4;
  const int wv   = tid >> 6;
  const int wm   = (wv & 1) * 32, wn = (wv >> 1) * 64;

  // staging: wave w, lane l -> LDS row w*16 + (l>>2), slot (l&3).
  // Source k-group is XOR-swizzled by row ((r>>1)&3; consistent under r+=64).
  const int rlo = wv*16 + (lane >> 2);
  const int sg  = ((lane & 3) ^ ((rlo >> 1) & 3)) * 8;    // shorts
  const bf16* ga = &A[(size_t)(row0 + rlo)*lda + sg];
  const bf16* gw = &W[(size_t)(col0 + rlo)*ldw + sg];
  const size_t w64 = (size_t)64 * ldw;

  auto STAGE = [&](int bb, int k0){
    unsigned short* Ab = As + bb*2048;
    unsigned short* Wb = Ws + bb*4096;
    gld_lds16(ga + k0,       Ab + wv*512);
    gld_lds16(gw + k0,       Wb + wv*512);
    gld_lds16(gw + k0 + w64, Wb + 2048 + wv*512);
  };

  f32x4 acc[2][4] = {};
  const int nt = K >> 5;    // 8/16/32 for our shapes

  STAGE(0, 0); STAGE(1, 32);     // 6 vm loads/wave in flight

  for (int t = 0; t < nt; ++t){
    const int b = t & 1;
    // tile t resident when <= 3 younger loads outstanding
    if (t + 1 < nt) asm volatile("s_waitcnt vmcnt(3)" ::: "memory");
    else            asm volatile("s_waitcnt vmcnt(0)" ::: "memory");
    __builtin_amdgcn_s_barrier();            // all waves' portions resident

    const unsigned short* Ab = As + b*2048;
    const unsigned short* Wb = Ws + b*4096;
    bf16x8 af[2], wf[4];
    #pragma unroll
    for (int i = 0; i < 2; i++){
      const int rA = wm + 16*i + m16;
      af[i] = *reinterpret_cast<const bf16x8*>(&Ab[rA*32 + ((quad ^ ((rA>>1)&3))<<3)]);
    }
    #pragma unroll
    for (int j = 0; j < 4; j++){
      const int rW = wn + 16*j + m16;
      wf[j] = *reinterpret_cast<const bf16x8*>(&Wb[rW*32 + ((quad ^ ((rW>>1)&3))<<3)]);
    }
    asm volatile("s_waitcnt lgkmcnt(0)" ::: "memory");   // this wave's reads done
    __builtin_amdgcn_sched_barrier(0);                   // rule #18
    __builtin_amdgcn_s_barrier();                        // all waves done with buf b

    if (t + 2 < nt) STAGE(b, (t + 2) << 5);              // refill freed buffer

    __builtin_amdgcn_s_setprio(1);
    #pragma unroll
    for (int i = 0; i < 2; i++)
      #pragma unroll
      for (int j = 0; j < 4; j++)
        acc[i][j] = __builtin_amdgcn_mfma_f32_16x16x32_bf16(af[i], wf[j], acc[i][j], 0, 0, 0);
    __builtin_amdgcn_s_setprio(0);
  }
  // all staging ds_reads completed before the final barrier -> safe to
  // overwrite lds with the repack tile now.

  // ---- epilogue phase 1: activate + write padded LDS tile ----
  // C/D layout col=lane&15, row=quad*4+reg (m89-verified)
  #pragma unroll
  for (int i = 0; i < 2; i++){
    #pragma unroll
    for (int j = 0; j < 4; j++){
      const int lcol = wn + 16*j + m16;
      const int col  = col0 + lcol;
      #pragma unroll
      for (int r2 = 0; r2 < 4; r2++){
        const int lrow = wm + 16*i + quad*4 + r2;
        const int row  = row0 + lrow;
        float v = acc[i][j][r2];
        if (FLAGS & 1) v += bias[col];
        if (ACT == 1)  v = fast_gelu(v);
        if (FLAGS & 2) v += __bfloat162float(res[(size_t)row*ldres + col]);
        if (FLAGS & 4) v += dscale[col] * __bfloat162float(res[(size_t)row*ldres + col]);
        bf16 bv = __float2bfloat16(v);
        lds[lrow*RPSTR + lcol] = *reinterpret_cast<unsigned short*>(&bv);
      }
    }
  }
  __syncthreads();

  // ---- epilogue phase 2: DENSE coalesced b128 stores ----
  // Per store instruction: wave covers 4 complete rows (16 lanes x 16B =
  // 256B contiguous per row). 4 instructions cover the 64x128 tile.
  {
    const int rr  = tid >> 4;           // 0..15 (row within 16-row group)
    const int c16 = (tid & 15) * 8;     // col in shorts (0..120)
    #pragma unroll
    for (int s = 0; s < 4; s++){
      const int orow = s*16 + rr;
      uint4 d = *reinterpret_cast<const uint4*>(&lds[orow*RPSTR + c16]);
      *reinterpret_cast<uint4*>(OB + (size_t)(row0 + orow)*ldc + col0 + c16) = d;
    }
  }

  // ---- epilogue phase 3 (Bu only): chunk-carry scan over the LDS tile ----
  // This block = chunk `by` x complex states [col0/2, col0/2+64) (interleaved
  // layout: local cols 2j/2j+1 = re/im of state col0/2+j). Recurrence is
  // bit-identical to the deleted scan_local (reads the SAME bf16 values).
  if (FLAGS & 8){
    if (tid < 64){
      const int sglob = (col0 >> 1) + tid;       // complex state 0..255
      float lr, li; lam_of(nu_log, th_log, sglob, lr, li);
      float ar = 0.f, ai = 0.f;
      for (int t = 0; t < CHUNK; t++){
        unsigned int pr = *reinterpret_cast<const unsigned int*>(&lds[t*RPSTR + 2*tid]);
        float br = __uint_as_float(pr << 16);            // low short = re
        float bi = __uint_as_float(pr & 0xffff0000u);    // high short = im
        float nr = fmaf(lr, ar, fmaf(-li, ai, br));
        float ni = fmaf(lr, ai, fmaf( li, ar, bi));
        ar = nr; ai = ni;
      }
      g_carry[(size_t)by*512 + 2*sglob]     = ar;
      g_carry[(size_t)by*512 + 2*sglob + 1] = ai;
    }
  }
}

// ---------------------------------------------------------------------------
// fp32 tiled GEMMs for the small ends (embed, out) — proven R12 structure.
// ---------------------------------------------------------------------------
__global__ __launch_bounds__(256) void emb_gemm(
    const float* __restrict__ x, const float* __restrict__ W,
    const float* __restrict__ b)
{
  __shared__ __align__(16) float Asx[16][68];
  __shared__ __align__(16) float Wsx[16][68];
  const int tid = threadIdx.x;
  const int tx = tid & 15, ty = tid >> 4;
  const int row0 = blockIdx.y * 64, col0 = blockIdx.x * 64;
  const int lc = tid & 15, lr = tid >> 4;
  float acc[4][4] = {};
  for (int k0 = 0; k0 < INDIM; k0 += 16){
    #pragma unroll
    for (int i = 0; i < 4; i++){
      Asx[lc][lr + 16*i] = x[(size_t)(row0 + lr + 16*i)*INDIM + k0 + lc];
      Wsx[lc][lr + 16*i] = W[(size_t)(col0 + lr + 16*i)*INDIM + k0 + lc];
    }
    __syncthreads();
    #pragma unroll
    for (int k = 0; k < 16; k++){
      float4 av = *reinterpret_cast<const float4*>(&Asx[k][ty*4]);
      float4 bv = *reinterpret_cast<const float4*>(&Wsx[k][tx*4]);
      float a[4] = {av.x, av.y, av.z, av.w};
      float b2[4] = {bv.x, bv.y, bv.z, bv.w};
      #pragma unroll
      for (int i = 0; i < 4; i++)
        #pragma unroll
        for (int j = 0; j < 4; j++)
          acc[i][j] = fmaf(a[i], b2[j], acc[i][j]);
    }
    __syncthreads();
  }
  #pragma unroll
  for (int i = 0; i < 4; i++){
    const int r = row0 + ty*4 + i;
    #pragma unroll
    for (int j = 0; j < 4; j++){
      const int cn = col0 + tx*4 + j;
      g_hb[(size_t)r*HIDD + cn] = __float2bfloat16(acc[i][j] + b[cn]);
    }
  }
}

__global__ __launch_bounds__(256) void out_gemm(
    const float* __restrict__ W, const float* __restrict__ b,
    float* __restrict__ out)
{
  __shared__ __align__(16) float Asx[16][68];
  __shared__ __align__(16) float Wsx[16][68];
  const int tid = threadIdx.x;
  const int tx = tid & 15, ty = tid >> 4;
  const int row0 = blockIdx.y * 64, col0 = blockIdx.x * 64;
  const int lc = tid & 15, lr = tid >> 4;
  float acc[4][4] = {};
  for (int k0 = 0; k0 < HIDD; k0 += 16){
    #pragma unroll
    for (int i = 0; i < 4; i++){
      Asx[lc][lr + 16*i] = __bfloat162float(g_hb[(size_t)(row0 + lr + 16*i)*HIDD + k0 + lc]);
      Wsx[lc][lr + 16*i] = W[(size_t)(col0 + lr + 16*i)*HIDD + k0 + lc];
    }
    __syncthreads();
    #pragma unroll
    for (int k = 0; k < 16; k++){
      float4 av = *reinterpret_cast<const float4*>(&Asx[k][ty*4]);
      float4 bv = *reinterpret_cast<const float4*>(&Wsx[k][tx*4]);
      float a[4] = {av.x, av.y, av.z, av.w};
      float b2[4] = {bv.x, bv.y, bv.z, bv.w};
      #pragma unroll
      for (int i = 0; i < 4; i++)
        #pragma unroll
        for (int j = 0; j < 4; j++)
          acc[i][j] = fmaf(a[i], b2[j], acc[i][j]);
    }
    __syncthreads();
  }
  #pragma unroll
  for (int i = 0; i < 4; i++){
    const int r = row0 + ty*4 + i;
    #pragma unroll
    for (int j = 0; j < 4; j++){
      const int cn = col0 + tx*4 + j;
      out[(size_t)r*OUTD + cn] = acc[i][j] + b[cn];
    }
  }
}

// ---------------------------------------------------------------------------
// Prefix accumulate over chunk carries + local re-scan seeded with prefix.
// Interleaved layout: thread s owns complex state s at uint-paired cols
// (2s, 2s+1) -> single dword load/store per token (fully coalesced).
// Overwrites g_bub in place with scan states.
// ---------------------------------------------------------------------------
__global__ __launch_bounds__(256) void scan_fix(
    const float* __restrict__ nu_log, const float* __restrict__ th_log)
{
  const int blk = blockIdx.x;
  const int c   = blk & (NCHUNK - 1);
  const int s   = threadIdx.x;          // complex state 0..255
  float lr, li; lam_of(nu_log, th_log, s, lr, li);
  float cr = 0.f, ci = 0.f;
  if (c > 0){
    float Tr = lr, Ti = li;              // lam^64 via 6 squarings
    #pragma unroll
    for (int i = 0; i < 6; i++){ float nr = Tr*Tr - Ti*Ti; Ti = 2.f*Tr*Ti; Tr = nr; }
    const int bstart = blk - c;
    for (int j = 0; j < c; j++){
      float2 e = *reinterpret_cast<const float2*>(&g_carry[(size_t)(bstart + j)*512 + 2*s]);
      float nr = fmaf(Tr, cr, fmaf(-Ti, ci, e.x));
      float ni = fmaf(Tr, ci, fmaf( Ti, cr, e.y));
      cr = nr; ci = ni;
    }
  }
  // inclusive scan with incoming state (cr,ci)
  float ar = cr, ai = ci;
  unsigned int* pb = reinterpret_cast<unsigned int*>(g_bub) + (size_t)blk*CHUNK*256 + s;
  for (int t = 0; t < CHUNK; t++){
    unsigned int pr = pb[(size_t)t*256];
    float br = __uint_as_float(pr << 16);
    float bi = __uint_as_float(pr & 0xffff0000u);
    float nr = fmaf(lr, ar, fmaf(-li, ai, br));
    float ni = fmaf(lr, ai, fmaf( li, ar, bi));
    ar = nr; ai = ni;
    bf16 hr = __float2bfloat16(ar), hi2 = __float2bfloat16(ai);
    unsigned int w = (unsigned int)(*reinterpret_cast<unsigned short*>(&hr))
                   | ((unsigned int)(*reinterpret_cast<unsigned short*>(&hi2)) << 16);
    pb[(size_t)t*256] = w;
  }
}

// Pack B_norm for ALL layers -> bf16, rows INTERLEAVED: row 2s=re_s, 2s+1=im_s
__global__ __launch_bounds__(256) void pack_B(
    const float* __restrict__ Bre, const float* __restrict__ Bim,
    const float* __restrict__ gl)
{
  int idx = blockIdx.x * 256 + threadIdx.x;      // 0..NLAYERS*65536-1
  int l = idx >> 16, within = idx & 65535;
  int s = within >> 8, h = within & 255;
  float g = expf(gl[l*STATE_D + s]);
  g_Bnb[(size_t)l*131072 + (size_t)(2*s  )*256 + h] = __float2bfloat16(Bre[idx] * g);
  g_Bnb[(size_t)l*131072 + (size_t)(2*s+1)*256 + h] = __float2bfloat16(Bim[idx] * g);
}

// Pack Cw for ALL layers -> bf16, cols INTERLEAVED: col 2s=Cre, 2s+1=-Cim
__global__ __launch_bounds__(256) void pack_C(
    const float* __restrict__ Cre, const float* __restrict__ Cim)
{
  int idx = blockIdx.x * 256 + threadIdx.x;      // 0..NLAYERS*65536-1
  int l = idx >> 16, within = idx & 65535;
  int h = within >> 8, s = within & 255;
  g_Cwb[(size_t)l*131072 + (size_t)h*512 + 2*s]     = __float2bfloat16( Cre[idx]);
  g_Cwb[(size_t)l*131072 + (size_t)h*512 + 2*s + 1] = __float2bfloat16(-Cim[idx]);
}

// Straight fp32 -> bf16 weight convert into selected buffer
__global__ __launch_bounds__(256) void conv_bf16(
    const float* __restrict__ src, int dstSel, int n)
{
  int i = blockIdx.x * 256 + threadIdx.x;
  if (i < n) bufb(dstSel)[i] = __float2bfloat16(src[i]);
}

// ---------------------------------------------------------------------------
extern "C" void kernel_launch(void* const* d_in, const int* in_sizes, int n_in,
                              void* d_out, int out_size, void* d_ws, size_t ws_size,
                              hipStream_t stream)
{
  (void)d_ws; (void)ws_size; (void)out_size; (void)n_in; (void)in_sizes;
  const float* x      = (const float*)d_in[0];
  const float* emb_W  = (const float*)d_in[1];
  const float* emb_b  = (const float*)d_in[2];
  const float* nu_log = (const float*)d_in[3];
  const float* th_log = (const float*)d_in[4];
  const float* ga_log = (const float*)d_in[5];
  const float* B_re   = (const float*)d_in[6];
  const float* B_im   = (const float*)d_in[7];
  const float* C_re   = (const float*)d_in[8];
  const float* C_im   = (const float*)d_in[9];
  const float* Dv     = (const float*)d_in[10];
  const float* Wh     = (const float*)d_in[11];
  const float* bh     = (const float*)d_in[12];
  const float* Wo     = (const float*)d_in[13];
  const float* bo     = (const float*)d_in[14];
  const float* out_W  = (const float*)d_in[15];
  const float* out_b  = (const float*)d_in[16];

  const dim3 blk(256);

  // ---- all weight packing upfront (independent of activations) ----
  pack_B<<<dim3(NLAYERS*256), blk, 0, stream>>>(B_re, B_im, ga_log);
  pack_C<<<dim3(NLAYERS*256), blk, 0, stream>>>(C_re, C_im);
  conv_bf16<<<dim3(NLAYERS*1024), blk, 0, stream>>>(Wh, SB_WHB, NLAYERS*262144);
  conv_bf16<<<dim3(NLAYERS*1024), blk, 0, stream>>>(Wo, SB_WOB, NLAYERS*262144);

  // embed: h = x @ emb_W^T + emb_b  -> g_hb (bf16 only)
  emb_gemm<<<dim3(HIDD/64, M_TOK/64), blk, 0, stream>>>(x, emb_W, emb_b);

  for (int l = 0; l < NLAYERS; l++){
    // Bu = h @ Bn^T (32768 x 512 x 256) -> g_bub bf16 + chunk carries (FLAGS 8)
    mfma_gemm<0, 8><<<dim3(4, M_TOK/64), blk, 0, stream>>>(
        SB_HB, HIDD, SB_BNB, l*131072, HIDD, SB_BUB, 512,
        nullptr, -1, 0, nullptr, HIDD,
        nu_log + l*STATE_D, th_log + l*STATE_D);

    // prefix + rescan (fp32 in registers, bf16 in memory, in-place states)
    scan_fix<<<dim3(M_TOK/CHUNK), blk, 0, stream>>>(nu_log + l*STATE_D, th_log + l*STATE_D);

    // y = states @ Cw^T + D*h   (32768 x 256 x 512) -> g_yb  [1024 blocks]
    mfma_gemm<0, 4><<<dim3(2, M_TOK/64), blk, 0, stream>>>(
        SB_BUB, 512, SB_CWB, l*131072, 512, SB_YB, HIDD,
        nullptr, SB_HB, HIDD, Dv + l*HIDD, 512, nullptr, nullptr);

    // z = gelu(y @ Wh^T + bh)   (32768 x 1024 x 256) -> g_zb  [4096 blocks]
    mfma_gemm<1, 1><<<dim3(8, M_TOK/64), blk, 0, stream>>>(
        SB_YB, HIDD, SB_WHB, l*262144, STATE_D, SB_ZB, MLPD,
        bh + l*MLPD, -1, 0, nullptr, STATE_D, nullptr, nullptr);

    // h = z @ Wo^T + bo + y     (32768 x 256 x 1024) -> g_hb  [1024 blocks]
    mfma_gemm<0, 3><<<dim3(2, M_TOK/64), blk, 0, stream>>>(
        SB_ZB, MLPD, SB_WOB, l*262144, MLPD, SB_HB, HIDD,
        bo + l*HIDD, SB_YB, HIDD, nullptr, MLPD, nullptr, nullptr);
  }

  // out = h @ out_W^T + out_b  (fp32 GEMM reading bf16 A, fp32 store)
  out_gemm<<<dim3(OUTD/64, M_TOK/64), blk, 0, stream>>>(out_W, out_b, (float*)d_out);
}

// Round 11
// 751.664 us; speedup vs baseline: 1.7010x; 1.0774x over previous
//
#include <hip/hip_runtime.h>
#include <hip/hip_bf16.h>
#include <math.h>

typedef __hip_bfloat16 bf16;
typedef __attribute__((ext_vector_type(8))) short bf16x8;   // 8 bf16 = 4 VGPR
typedef __attribute__((ext_vector_type(4))) float f32x4;    // MFMA acc

#define BATCH   16
#define SEQLEN  2048
#define INDIM   64
#define HIDD    256
#define STATE_D 256
#define MLPD    1024
#define OUTD    128
#define NLAYERS 4
#define M_TOK   (BATCH*SEQLEN)     // 32768 tokens
#define CHUNK   64
#define NCHUNK  (SEQLEN/CHUNK)     // 32 chunks per batch

// ---- ALL-BF16 activation chain; complex-interleaved states (R10) ---------
__device__ float g_carry[512*512];          // fp32 carries [chunk][2s|2s+1]
__device__ bf16  g_hb [(size_t)M_TOK*256];
__device__ bf16  g_yb [(size_t)M_TOK*256];
__device__ bf16  g_bub[(size_t)M_TOK*512];  // raw Bu, then scan states (in place)
// per-layer packed weights (hoisted out of the layer loop)
__device__ bf16  g_Bnb[NLAYERS*512*256];    // B_norm rows interleaved: 2s=re, 2s+1=im
__device__ bf16  g_Cwb[NLAYERS*256*512];    // cols interleaved: 2s=Cre, 2s+1=-Cim
__device__ bf16  g_Whb[NLAYERS*1024*256];
__device__ bf16  g_Wob[NLAYERS*256*1024];

#define SB_HB  0
#define SB_YB  1
#define SB_BUB 2
#define SB_BNB 4
#define SB_CWB 5
#define SB_WHB 6
#define SB_WOB 7

__device__ __forceinline__ bf16* bufb(int sel){
  switch(sel){
    case SB_HB:  return g_hb;  case SB_YB:  return g_yb;
    case SB_BUB: return g_bub;
    case SB_BNB: return g_Bnb; case SB_CWB: return g_Cwb;
    case SB_WHB: return g_Whb; default:     return g_Wob; }
}

// async global->LDS, 16B per lane. LDS dest is wave-uniform base + lane*16.
__device__ __forceinline__ void gld_lds16(const void* g, void* l){
  __builtin_amdgcn_global_load_lds(
      (const __attribute__((address_space(1))) unsigned int*)g,
      (__attribute__((address_space(3))) unsigned int*)l, 16, 0, 0);
}

// Branch-free exact-GELU via Abramowitz-Stegun 7.1.26 erf (|err|<=1.5e-7).
__device__ __forceinline__ float fast_gelu(float v){
  const float x  = v * 0.70710678118654752f;
  const float ax = fabsf(x);
  const float t  = __builtin_amdgcn_rcpf(fmaf(0.3275911f, ax, 1.0f));
  float p = fmaf(t, 1.061405429f, -1.453152027f);
  p = fmaf(t, p, 1.421413741f);
  p = fmaf(t, p, -0.284496736f);
  p = fmaf(t, p, 0.254829592f);
  p = p * t;
  const float e = __expf(-ax * ax);
  const float erf_ax = fmaf(-p, e, 1.0f);
  const float erf_x  = copysignf(erf_ax, x);
  return 0.5f * v * (1.0f + erf_x);
}

// pairwise add of 2 packed bf16 lanes in fp32, repack to bf16
__device__ __forceinline__ unsigned int bf2_add(unsigned int a, unsigned int b){
  float alo = __uint_as_float(a << 16), ahi = __uint_as_float(a & 0xffff0000u);
  float blo = __uint_as_float(b << 16), bhi = __uint_as_float(b & 0xffff0000u);
  bf16 l = __float2bfloat16(alo + blo);
  bf16 h = __float2bfloat16(ahi + bhi);
  return (unsigned int)(*reinterpret_cast<unsigned short*>(&l))
       | ((unsigned int)(*reinterpret_cast<unsigned short*>(&h)) << 16);
}

// lam_s = exp(-exp(nu)) * (cos(exp(th)) + i sin(exp(th)))
__device__ __forceinline__ void lam_of(const float* __restrict__ nu_log,
                                       const float* __restrict__ th_log,
                                       int s, float& lr, float& li)
{
  float nu  = expf(nu_log[s]);
  float th  = expf(th_log[s]);
  float mag = expf(-nu);
  lr = mag * cosf(th);
  li = mag * sinf(th);
}

// ---------------------------------------------------------------------------
// MFMA GEMM (Bu and y only now): 64x128 tile, 4 waves, BK=32, 2-deep ring,
// counted vmcnt, T2 source-swizzle (conflicts 0), XCD swizzle, LDS-repack
// epilogue with DENSE b128 stores (R9).
// FLAGS: 1=bias 2=+res 4=+dscale[n]*res 8=CHUNK-CARRY (Bu epilogue scan).
// ---------------------------------------------------------------------------
#define RPSTR 136

template<int ACT, int FLAGS>
__global__ __launch_bounds__(256, 6) void mfma_gemm(
    int aSel, int lda, int wSel, int wOff, int ldw,
    int oSel, int ldc,
    const float* __restrict__ bias,
    int rSel, int ldres,
    const float* __restrict__ dscale,
    int K,
    const float* __restrict__ nu_log,
    const float* __restrict__ th_log)
{
  const bf16* A = bufb(aSel);
  const bf16* W = bufb(wSel) + wOff;
  bf16* OB = bufb(oSel);
  const bf16* res = (rSel >= 0) ? bufb(rSel) : nullptr;

  __shared__ __align__(16) unsigned short lds[12288];
  unsigned short* As = lds;          // 2 x 2048 shorts
  unsigned short* Ws = lds + 4096;   // 2 x 4096 shorts

  const int gx = gridDim.x;
  const int nwg = gx * gridDim.y;
  const int orig = blockIdx.y * gx + blockIdx.x;
  const int q = nwg >> 3, r = nwg & 7;
  const int xcd = orig & 7, idx = orig >> 3;
  const int wg = (xcd < r ? xcd*(q+1) : r*(q+1) + (xcd-r)*q) + idx;
  const int bx = wg % gx, by = wg / gx;

  const int tid  = threadIdx.x;
  const int row0 = by * 64, col0 = bx * 128;
  const int lane = tid & 63;
  const int m16  = lane & 15, quad = lane >> 4;
  const int wv   = tid >> 6;
  const int wm   = (wv & 1) * 32, wn = (wv >> 1) * 64;

  const int rlo = wv*16 + (lane >> 2);
  const int sg  = ((lane & 3) ^ ((rlo >> 1) & 3)) * 8;    // shorts
  const bf16* ga = &A[(size_t)(row0 + rlo)*lda + sg];
  const bf16* gw = &W[(size_t)(col0 + rlo)*ldw + sg];
  const size_t w64 = (size_t)64 * ldw;

  auto STAGE = [&](int bb, int k0){
    unsigned short* Ab = As + bb*2048;
    unsigned short* Wb = Ws + bb*4096;
    gld_lds16(ga + k0,       Ab + wv*512);
    gld_lds16(gw + k0,       Wb + wv*512);
    gld_lds16(gw + k0 + w64, Wb + 2048 + wv*512);
  };

  f32x4 acc[2][4] = {};
  const int nt = K >> 5;

  STAGE(0, 0); STAGE(1, 32);

  for (int t = 0; t < nt; ++t){
    const int b = t & 1;
    if (t + 1 < nt) asm volatile("s_waitcnt vmcnt(3)" ::: "memory");
    else            asm volatile("s_waitcnt vmcnt(0)" ::: "memory");
    __builtin_amdgcn_s_barrier();

    const unsigned short* Ab = As + b*2048;
    const unsigned short* Wb = Ws + b*4096;
    bf16x8 af[2], wf[4];
    #pragma unroll
    for (int i = 0; i < 2; i++){
      const int rA = wm + 16*i + m16;
      af[i] = *reinterpret_cast<const bf16x8*>(&Ab[rA*32 + ((quad ^ ((rA>>1)&3))<<3)]);
    }
    #pragma unroll
    for (int j = 0; j < 4; j++){
      const int rW = wn + 16*j + m16;
      wf[j] = *reinterpret_cast<const bf16x8*>(&Wb[rW*32 + ((quad ^ ((rW>>1)&3))<<3)]);
    }
    asm volatile("s_waitcnt lgkmcnt(0)" ::: "memory");
    __builtin_amdgcn_sched_barrier(0);
    __builtin_amdgcn_s_barrier();

    if (t + 2 < nt) STAGE(b, (t + 2) << 5);

    __builtin_amdgcn_s_setprio(1);
    #pragma unroll
    for (int i = 0; i < 2; i++)
      #pragma unroll
      for (int j = 0; j < 4; j++)
        acc[i][j] = __builtin_amdgcn_mfma_f32_16x16x32_bf16(af[i], wf[j], acc[i][j], 0, 0, 0);
    __builtin_amdgcn_s_setprio(0);
  }

  // epilogue phase 1: activate + write padded LDS tile
  #pragma unroll
  for (int i = 0; i < 2; i++){
    #pragma unroll
    for (int j = 0; j < 4; j++){
      const int lcol = wn + 16*j + m16;
      const int col  = col0 + lcol;
      #pragma unroll
      for (int r2 = 0; r2 < 4; r2++){
        const int lrow = wm + 16*i + quad*4 + r2;
        const int row  = row0 + lrow;
        float v = acc[i][j][r2];
        if (FLAGS & 1) v += bias[col];
        if (ACT == 1)  v = fast_gelu(v);
        if (FLAGS & 2) v += __bfloat162float(res[(size_t)row*ldres + col]);
        if (FLAGS & 4) v += dscale[col] * __bfloat162float(res[(size_t)row*ldres + col]);
        bf16 bv = __float2bfloat16(v);
        lds[lrow*RPSTR + lcol] = *reinterpret_cast<unsigned short*>(&bv);
      }
    }
  }
  __syncthreads();

  // epilogue phase 2: DENSE coalesced b128 stores
  {
    const int rr  = tid >> 4;
    const int c16 = (tid & 15) * 8;
    #pragma unroll
    for (int s = 0; s < 4; s++){
      const int orow = s*16 + rr;
      uint4 d = *reinterpret_cast<const uint4*>(&lds[orow*RPSTR + c16]);
      *reinterpret_cast<uint4*>(OB + (size_t)(row0 + orow)*ldc + col0 + c16) = d;
    }
  }

  // epilogue phase 3 (Bu only): chunk-carry scan over the LDS tile
  if (FLAGS & 8){
    if (tid < 64){
      const int sglob = (col0 >> 1) + tid;
      float lr, li; lam_of(nu_log, th_log, sglob, lr, li);
      float ar = 0.f, ai = 0.f;
      for (int t = 0; t < CHUNK; t++){
        unsigned int pr = *reinterpret_cast<const unsigned int*>(&lds[t*RPSTR + 2*tid]);
        float br = __uint_as_float(pr << 16);
        float bi = __uint_as_float(pr & 0xffff0000u);
        float nr = fmaf(lr, ar, fmaf(-li, ai, br));
        float ni = fmaf(lr, ai, fmaf( li, ar, bi));
        ar = nr; ai = ni;
      }
      g_carry[(size_t)by*512 + 2*sglob]     = ar;
      g_carry[(size_t)by*512 + 2*sglob + 1] = ai;
    }
  }
}

// ---------------------------------------------------------------------------
// FUSED MLP (R11): h_new = gelu(y @ Wh^T + bh) @ Wo^T + bo + y, per-block 64
// tokens, g_zb never materialized (eliminates 130 MB/layer HBM round-trip).
// 8 sub-chunks of MLPD=128:
//   phase A: z_sub[64x128] = gelu(y @ Wh_sub^T + bh)  (K=256, verified ring)
//            -> LDS zbuf[64][132] only (stride 132: 2-way bank alias = free)
//   phase B: accB[64x256] += z_sub @ Wo_sub^T         (K=128, A from zbuf,
//            Wo 256x32 tiles via counted-vmcnt ring, 4 glds/step)
// Phase-B prologue issued before the gelu epilogue (latency hides under VALU).
// Final: +bo, two-half repack via zbuf, +y residual added vectorized at the
// coalesced store (uint4 bf16-pair adds). LDS 56.5 KB -> 2 blocks/CU; grid
// 512 -> all blocks resident.
// Ring-handoff safety: Ws reuse A->B and B->A(mc+1) each guarded by the
// final read-barrier of the preceding k-loop; zbuf guarded by __syncthreads.
// ---------------------------------------------------------------------------
__global__ __launch_bounds__(256, 2) void fused_mlp(
    int whOff, int woOff,
    const float* __restrict__ bh, const float* __restrict__ bo)
{
  const bf16* Wh = g_Whb + whOff;
  const bf16* Wo = g_Wob + woOff;

  __shared__ __align__(16) unsigned short As[2*2048];    // y staging (8 KB)
  __shared__ __align__(16) unsigned short Ws[2*8192];    // Wh/Wo ring (32 KB)
  __shared__ __align__(16) unsigned short zbuf[64*132];  // z_sub (16.5 KB)

  const int tid  = threadIdx.x;
  const int row0 = blockIdx.x * 64;
  const int lane = tid & 63;
  const int m16  = lane & 15, quad = lane >> 4;
  const int wv   = tid >> 6;
  const int wm   = (wv & 1) * 32;
  const int wnA  = (wv >> 1) * 64;     // phase A col group (z cols)
  const int wnB  = (wv >> 1) * 128;    // phase B col group (h cols)

  const int rlo = wv*16 + (lane >> 2);
  const int sg  = ((lane & 3) ^ ((rlo >> 1) & 3)) * 8;   // shorts

  const bf16* ga = g_yb + (size_t)(row0 + rlo)*HIDD + sg;

  f32x4 accB[2][8] = {};

  for (int mc = 0; mc < 8; ++mc){
    const bf16* gwh = Wh + (size_t)(mc*128 + rlo)*HIDD + sg;
    const bf16* gwo = Wo + (size_t)rlo*MLPD + mc*128 + sg;

    auto STAGE_A = [&](int b, int k0){
      gld_lds16(ga + k0,            As + b*2048 + wv*512);
      gld_lds16(gwh + k0,           Ws + b*8192 + wv*512);
      gld_lds16(gwh + k0 + 64*HIDD, Ws + b*8192 + 2048 + wv*512);
    };
    auto STAGE_B = [&](int b, int ks){
      const bf16* src = gwo + ks*32;
      #pragma unroll
      for (int g = 0; g < 4; g++)
        gld_lds16(src + (size_t)g*64*MLPD, Ws + b*8192 + g*2048 + wv*512);
    };

    // ---- phase A: z_sub = gelu(y @ Wh_sub^T + bh), K=256 ----
    f32x4 accA[2][4] = {};
    STAGE_A(0, 0); STAGE_A(1, 32);
    for (int t = 0; t < 8; ++t){
      const int b = t & 1;
      if (t + 1 < 8) asm volatile("s_waitcnt vmcnt(3)" ::: "memory");
      else           asm volatile("s_waitcnt vmcnt(0)" ::: "memory");
      __builtin_amdgcn_s_barrier();
      const unsigned short* Ab = As + b*2048;
      const unsigned short* Wb = Ws + b*8192;
      bf16x8 af[2], wf[4];
      #pragma unroll
      for (int i = 0; i < 2; i++){
        const int rA = wm + 16*i + m16;
        af[i] = *reinterpret_cast<const bf16x8*>(&Ab[rA*32 + ((quad ^ ((rA>>1)&3))<<3)]);
      }
      #pragma unroll
      for (int j = 0; j < 4; j++){
        const int rW = wnA + 16*j + m16;
        wf[j] = *reinterpret_cast<const bf16x8*>(&Wb[rW*32 + ((quad ^ ((rW>>1)&3))<<3)]);
      }
      asm volatile("s_waitcnt lgkmcnt(0)" ::: "memory");
      __builtin_amdgcn_sched_barrier(0);
      __builtin_amdgcn_s_barrier();
      if (t + 2 < 8) STAGE_A(b, (t + 2) << 5);
      __builtin_amdgcn_s_setprio(1);
      #pragma unroll
      for (int i = 0; i < 2; i++)
        #pragma unroll
        for (int j = 0; j < 4; j++)
          accA[i][j] = __builtin_amdgcn_mfma_f32_16x16x32_bf16(af[i], wf[j], accA[i][j], 0, 0, 0);
      __builtin_amdgcn_s_setprio(0);
    }
    // Ws ring fully read (final barrier above) -> prefetch phase B tiles now;
    // their HBM latency hides under the gelu epilogue below.
    STAGE_B(0, 0); STAGE_B(1, 1);

    // epilogue A: bias + gelu -> zbuf (no global write)
    #pragma unroll
    for (int i = 0; i < 2; i++){
      #pragma unroll
      for (int j = 0; j < 4; j++){
        const int lcol = wnA + 16*j + m16;
        const float bb = bh[mc*128 + lcol];
        #pragma unroll
        for (int r2 = 0; r2 < 4; r2++){
          const int lrow = wm + 16*i + quad*4 + r2;
          float v = fast_gelu(accA[i][j][r2] + bb);
          bf16 bv = __float2bfloat16(v);
          zbuf[lrow*132 + lcol] = *reinterpret_cast<unsigned short*>(&bv);
        }
      }
    }
    __syncthreads();   // zbuf visible to all waves

    // ---- phase B: accB += z_sub @ Wo_sub^T, K=128 ----
    for (int ks = 0; ks < 4; ++ks){
      const int b = ks & 1;
      if (ks + 1 < 4) asm volatile("s_waitcnt vmcnt(4)" ::: "memory");
      else            asm volatile("s_waitcnt vmcnt(0)" ::: "memory");
      __builtin_amdgcn_s_barrier();
      const unsigned short* Wb = Ws + b*8192;
      bf16x8 af[2], wf[8];
      #pragma unroll
      for (int i = 0; i < 2; i++){
        const int rA = wm + 16*i + m16;
        af[i] = *reinterpret_cast<const bf16x8*>(&zbuf[rA*132 + ks*32 + quad*8]);
      }
      #pragma unroll
      for (int j = 0; j < 8; j++){
        const int rW = wnB + 16*j + m16;
        wf[j] = *reinterpret_cast<const bf16x8*>(&Wb[rW*32 + ((quad ^ ((rW>>1)&3))<<3)]);
      }
      asm volatile("s_waitcnt lgkmcnt(0)" ::: "memory");
      __builtin_amdgcn_sched_barrier(0);
      __builtin_amdgcn_s_barrier();
      if (ks + 2 < 4) STAGE_B(b, ks + 2);
      __builtin_amdgcn_s_setprio(1);
      #pragma unroll
      for (int i = 0; i < 2; i++)
        #pragma unroll
        for (int j = 0; j < 8; j++)
          accB[i][j] = __builtin_amdgcn_mfma_f32_16x16x32_bf16(af[i], wf[j], accB[i][j], 0, 0, 0);
      __builtin_amdgcn_s_setprio(0);
    }
  }

  // ---- final epilogue: h = accB + bo + y, two col-halves via zbuf ----
  #pragma unroll
  for (int n = 0; n < 2; n++){
    __syncthreads();                    // zbuf free (phase-B reads done / prev stores done)
    if ((wv >> 1) == n){
      #pragma unroll
      for (int i = 0; i < 2; i++){
        #pragma unroll
        for (int j = 0; j < 8; j++){
          const int lcol = 16*j + m16;  // wnB - n*128 + 16j + m16
          const float bb = bo[n*128 + lcol];
          #pragma unroll
          for (int r2 = 0; r2 < 4; r2++){
            const int lrow = wm + 16*i + quad*4 + r2;
            float v = accB[i][j][r2] + bb;
            bf16 bv = __float2bfloat16(v);
            zbuf[lrow*132 + lcol] = *reinterpret_cast<unsigned short*>(&bv);
          }
        }
      }
    }
    __syncthreads();
    const int rr = tid >> 4, c16 = (tid & 15) * 8;
    #pragma unroll
    for (int s = 0; s < 4; s++){
      const int orow = s*16 + rr;
      uint4 hv = *reinterpret_cast<const uint4*>(&zbuf[orow*132 + c16]);
      const size_t go = (size_t)(row0 + orow)*HIDD + n*128 + c16;
      uint4 yv = *reinterpret_cast<const uint4*>(g_yb + go);
      uint4 o;
      o.x = bf2_add(hv.x, yv.x); o.y = bf2_add(hv.y, yv.y);
      o.z = bf2_add(hv.z, yv.z); o.w = bf2_add(hv.w, yv.w);
      *reinterpret_cast<uint4*>(g_hb + go) = o;
    }
  }
}

// ---------------------------------------------------------------------------
// fp32 tiled GEMMs for the small ends (embed, out) — proven R12 structure.
// ---------------------------------------------------------------------------
__global__ __launch_bounds__(256) void emb_gemm(
    const float* __restrict__ x, const float* __restrict__ W,
    const float* __restrict__ b)
{
  __shared__ __align__(16) float Asx[16][68];
  __shared__ __align__(16) float Wsx[16][68];
  const int tid = threadIdx.x;
  const int tx = tid & 15, ty = tid >> 4;
  const int row0 = blockIdx.y * 64, col0 = blockIdx.x * 64;
  const int lc = tid & 15, lr = tid >> 4;
  float acc[4][4] = {};
  for (int k0 = 0; k0 < INDIM; k0 += 16){
    #pragma unroll
    for (int i = 0; i < 4; i++){
      Asx[lc][lr + 16*i] = x[(size_t)(row0 + lr + 16*i)*INDIM + k0 + lc];
      Wsx[lc][lr + 16*i] = W[(size_t)(col0 + lr + 16*i)*INDIM + k0 + lc];
    }
    __syncthreads();
    #pragma unroll
    for (int k = 0; k < 16; k++){
      float4 av = *reinterpret_cast<const float4*>(&Asx[k][ty*4]);
      float4 bv = *reinterpret_cast<const float4*>(&Wsx[k][tx*4]);
      float a[4] = {av.x, av.y, av.z, av.w};
      float b2[4] = {bv.x, bv.y, bv.z, bv.w};
      #pragma unroll
      for (int i = 0; i < 4; i++)
        #pragma unroll
        for (int j = 0; j < 4; j++)
          acc[i][j] = fmaf(a[i], b2[j], acc[i][j]);
    }
    __syncthreads();
  }
  #pragma unroll
  for (int i = 0; i < 4; i++){
    const int r = row0 + ty*4 + i;
    #pragma unroll
    for (int j = 0; j < 4; j++){
      const int cn = col0 + tx*4 + j;
      g_hb[(size_t)r*HIDD + cn] = __float2bfloat16(acc[i][j] + b[cn]);
    }
  }
}

__global__ __launch_bounds__(256) void out_gemm(
    const float* __restrict__ W, const float* __restrict__ b,
    float* __restrict__ out)
{
  __shared__ __align__(16) float Asx[16][68];
  __shared__ __align__(16) float Wsx[16][68];
  const int tid = threadIdx.x;
  const int tx = tid & 15, ty = tid >> 4;
  const int row0 = blockIdx.y * 64, col0 = blockIdx.x * 64;
  const int lc = tid & 15, lr = tid >> 4;
  float acc[4][4] = {};
  for (int k0 = 0; k0 < HIDD; k0 += 16){
    #pragma unroll
    for (int i = 0; i < 4; i++){
      Asx[lc][lr + 16*i] = __bfloat162float(g_hb[(size_t)(row0 + lr + 16*i)*HIDD + k0 + lc]);
      Wsx[lc][lr + 16*i] = W[(size_t)(col0 + lr + 16*i)*HIDD + k0 + lc];
    }
    __syncthreads();
    #pragma unroll
    for (int k = 0; k < 16; k++){
      float4 av = *reinterpret_cast<const float4*>(&Asx[k][ty*4]);
      float4 bv = *reinterpret_cast<const float4*>(&Wsx[k][tx*4]);
      float a[4] = {av.x, av.y, av.z, av.w};
      float b2[4] = {bv.x, bv.y, bv.z, bv.w};
      #pragma unroll
      for (int i = 0; i < 4; i++)
        #pragma unroll
        for (int j = 0; j < 4; j++)
          acc[i][j] = fmaf(a[i], b2[j], acc[i][j]);
    }
    __syncthreads();
  }
  #pragma unroll
  for (int i = 0; i < 4; i++){
    const int r = row0 + ty*4 + i;
    #pragma unroll
    for (int j = 0; j < 4; j++){
      const int cn = col0 + tx*4 + j;
      out[(size_t)r*OUTD + cn] = acc[i][j] + b[cn];
    }
  }
}

// ---------------------------------------------------------------------------
// Prefix accumulate over chunk carries + local re-scan seeded with prefix.
// Interleaved layout: thread s owns complex state s at uint-paired cols.
// ---------------------------------------------------------------------------
__global__ __launch_bounds__(256) void scan_fix(
    const float* __restrict__ nu_log, const float* __restrict__ th_log)
{
  const int blk = blockIdx.x;
  const int c   = blk & (NCHUNK - 1);
  const int s   = threadIdx.x;
  float lr, li; lam_of(nu_log, th_log, s, lr, li);
  float cr = 0.f, ci = 0.f;
  if (c > 0){
    float Tr = lr, Ti = li;
    #pragma unroll
    for (int i = 0; i < 6; i++){ float nr = Tr*Tr - Ti*Ti; Ti = 2.f*Tr*Ti; Tr = nr; }
    const int bstart = blk - c;
    for (int j = 0; j < c; j++){
      float2 e = *reinterpret_cast<const float2*>(&g_carry[(size_t)(bstart + j)*512 + 2*s]);
      float nr = fmaf(Tr, cr, fmaf(-Ti, ci, e.x));
      float ni = fmaf(Tr, ci, fmaf( Ti, cr, e.y));
      cr = nr; ci = ni;
    }
  }
  float ar = cr, ai = ci;
  unsigned int* pb = reinterpret_cast<unsigned int*>(g_bub) + (size_t)blk*CHUNK*256 + s;
  for (int t = 0; t < CHUNK; t++){
    unsigned int pr = pb[(size_t)t*256];
    float br = __uint_as_float(pr << 16);
    float bi = __uint_as_float(pr & 0xffff0000u);
    float nr = fmaf(lr, ar, fmaf(-li, ai, br));
    float ni = fmaf(lr, ai, fmaf( li, ar, bi));
    ar = nr; ai = ni;
    bf16 hr = __float2bfloat16(ar), hi2 = __float2bfloat16(ai);
    unsigned int w = (unsigned int)(*reinterpret_cast<unsigned short*>(&hr))
                   | ((unsigned int)(*reinterpret_cast<unsigned short*>(&hi2)) << 16);
    pb[(size_t)t*256] = w;
  }
}

// Pack B_norm for ALL layers -> bf16, rows INTERLEAVED: row 2s=re_s, 2s+1=im_s
__global__ __launch_bounds__(256) void pack_B(
    const float* __restrict__ Bre, const float* __restrict__ Bim,
    const float* __restrict__ gl)
{
  int idx = blockIdx.x * 256 + threadIdx.x;
  int l = idx >> 16, within = idx & 65535;
  int s = within >> 8, h = within & 255;
  float g = expf(gl[l*STATE_D + s]);
  g_Bnb[(size_t)l*131072 + (size_t)(2*s  )*256 + h] = __float2bfloat16(Bre[idx] * g);
  g_Bnb[(size_t)l*131072 + (size_t)(2*s+1)*256 + h] = __float2bfloat16(Bim[idx] * g);
}

// Pack Cw for ALL layers -> bf16, cols INTERLEAVED: col 2s=Cre, 2s+1=-Cim
__global__ __launch_bounds__(256) void pack_C(
    const float* __restrict__ Cre, const float* __restrict__ Cim)
{
  int idx = blockIdx.x * 256 + threadIdx.x;
  int l = idx >> 16, within = idx & 65535;
  int h = within >> 8, s = within & 255;
  g_Cwb[(size_t)l*131072 + (size_t)h*512 + 2*s]     = __float2bfloat16( Cre[idx]);
  g_Cwb[(size_t)l*131072 + (size_t)h*512 + 2*s + 1] = __float2bfloat16(-Cim[idx]);
}

// Straight fp32 -> bf16 weight convert into selected buffer
__global__ __launch_bounds__(256) void conv_bf16(
    const float* __restrict__ src, int dstSel, int n)
{
  int i = blockIdx.x * 256 + threadIdx.x;
  if (i < n) bufb(dstSel)[i] = __float2bfloat16(src[i]);
}

// ---------------------------------------------------------------------------
extern "C" void kernel_launch(void* const* d_in, const int* in_sizes, int n_in,
                              void* d_out, int out_size, void* d_ws, size_t ws_size,
                              hipStream_t stream)
{
  (void)d_ws; (void)ws_size; (void)out_size; (void)n_in; (void)in_sizes;
  const float* x      = (const float*)d_in[0];
  const float* emb_W  = (const float*)d_in[1];
  const float* emb_b  = (const float*)d_in[2];
  const float* nu_log = (const float*)d_in[3];
  const float* th_log = (const float*)d_in[4];
  const float* ga_log = (const float*)d_in[5];
  const float* B_re   = (const float*)d_in[6];
  const float* B_im   = (const float*)d_in[7];
  const float* C_re   = (const float*)d_in[8];
  const float* C_im   = (const float*)d_in[9];
  const float* Dv     = (const float*)d_in[10];
  const float* Wh     = (const float*)d_in[11];
  const float* bh     = (const float*)d_in[12];
  const float* Wo     = (const float*)d_in[13];
  const float* bo     = (const float*)d_in[14];
  const float* out_W  = (const float*)d_in[15];
  const float* out_b  = (const float*)d_in[16];

  const dim3 blk(256);

  // ---- all weight packing upfront ----
  pack_B<<<dim3(NLAYERS*256), blk, 0, stream>>>(B_re, B_im, ga_log);
  pack_C<<<dim3(NLAYERS*256), blk, 0, stream>>>(C_re, C_im);
  conv_bf16<<<dim3(NLAYERS*1024), blk, 0, stream>>>(Wh, SB_WHB, NLAYERS*262144);
  conv_bf16<<<dim3(NLAYERS*1024), blk, 0, stream>>>(Wo, SB_WOB, NLAYERS*262144);

  // embed: h = x @ emb_W^T + emb_b  -> g_hb
  emb_gemm<<<dim3(HIDD/64, M_TOK/64), blk, 0, stream>>>(x, emb_W, emb_b);

  for (int l = 0; l < NLAYERS; l++){
    // Bu = h @ Bn^T (32768 x 512 x 256) -> g_bub bf16 + chunk carries
    mfma_gemm<0, 8><<<dim3(4, M_TOK/64), blk, 0, stream>>>(
        SB_HB, HIDD, SB_BNB, l*131072, HIDD, SB_BUB, 512,
        nullptr, -1, 0, nullptr, HIDD,
        nu_log + l*STATE_D, th_log + l*STATE_D);

    // prefix + rescan (in-place states)
    scan_fix<<<dim3(M_TOK/CHUNK), blk, 0, stream>>>(nu_log + l*STATE_D, th_log + l*STATE_D);

    // y = states @ Cw^T + D*h -> g_yb
    mfma_gemm<0, 4><<<dim3(2, M_TOK/64), blk, 0, stream>>>(
        SB_BUB, 512, SB_CWB, l*131072, 512, SB_YB, HIDD,
        nullptr, SB_HB, HIDD, Dv + l*HIDD, 512, nullptr, nullptr);

    // h = gelu(y @ Wh^T + bh) @ Wo^T + bo + y  (fused, no g_zb)
    fused_mlp<<<dim3(M_TOK/64), blk, 0, stream>>>(
        l*262144, l*262144, bh + l*MLPD, bo + l*HIDD);
  }

  // out = h @ out_W^T + out_b
  out_gemm<<<dim3(OUTD/64, M_TOK/64), blk, 0, stream>>>(out_W, out_b, (float*)d_out);
}